// Round 7
// baseline (288.895 us; speedup 1.0000x reference)
//
#include <hip/hip_runtime.h>
#include <hip/hip_bf16.h>

typedef __attribute__((ext_vector_type(4))) float f32x4;
typedef __attribute__((ext_vector_type(8))) short s16x8;

#define NROWS 4096
#define DMODEL 256
#define NHEAD 8
#define HDIM 32
#define PSTRIDE 72     // halfwords per P-scratch row: 144 B, 16B-aligned
#define OSTRIDE 33     // f32 per sO row (32 q + 1 pad)
#define M2C 24.0f      // fixed softmax max (log2 domain)
#define NM (NROWS * DMODEL)

__device__ __forceinline__ short bf16r(float f) {
    union { float f; unsigned u; } v; v.f = f;
    unsigned r = v.u + 0x7fffu + ((v.u >> 16) & 1u);  // RNE
    return (short)(r >> 16);
}

__device__ __forceinline__ float fexp2(float x) {
    float r;
    asm("v_exp_f32 %0, %1" : "=v"(r) : "v"(x));
    return r;
}

__device__ __forceinline__ unsigned pk_bf16(float a, float b) {
#if __has_builtin(__builtin_amdgcn_cvt_pk_bf16_f32)
    typedef __bf16 bf2 __attribute__((ext_vector_type(2)));
    union { bf2 h; unsigned u; } c;
    c.h = __builtin_amdgcn_cvt_pk_bf16_f32(a, b);
    return c.u;
#else
    return (unsigned)(unsigned short)bf16r(a) | ((unsigned)(unsigned short)bf16r(b) << 16);
#endif
}

__device__ __forceinline__ s16x8 pack8(float4 a, float4 b) {
    s16x8 r;
    r[0] = bf16r(a.x); r[1] = bf16r(a.y); r[2] = bf16r(a.z); r[3] = bf16r(a.w);
    r[4] = bf16r(b.x); r[5] = bf16r(b.y); r[6] = bf16r(b.z); r[7] = bf16r(b.w);
    return r;
}

// ---------------------------------------------------------------------------
// Fat prep: blocks [0,2048): adj -> bitmask (diag OR'd), 32 wave-tasks each.
// Blocks [2048,2304): pack 6 weight matrices to bf16 (Wq,Wk,Wv,Wo,W1,W2).
__global__ __launch_bounds__(256) void prep_kernel(const int* __restrict__ adj,
                                                   unsigned* __restrict__ mask,
                                                   const float* __restrict__ Wq,
                                                   const float* __restrict__ Wk,
                                                   const float* __restrict__ Wv,
                                                   const float* __restrict__ Wo,
                                                   const float* __restrict__ W1,
                                                   const float* __restrict__ W2,
                                                   short* __restrict__ wout) {
    const int lane = threadIdx.x & 63;
    if (blockIdx.x < 2048) {
        const int waveid = blockIdx.x * 4 + (threadIdx.x >> 6);  // 0..8191
#pragma unroll
        for (int i = 0; i < 32; ++i) {
            const int task = waveid + i * 8192;       // 0..262143 (row,chunk)
            const int row = task >> 6, chunk = task & 63;
            const int c = chunk * 64 + lane;
            int a = adj[(size_t)row * NROWS + c];
            unsigned long long m = __ballot(a > 0 || c == row);
            if (lane == 0)      mask[row * 128 + chunk * 2]     = (unsigned)m;
            else if (lane == 1) mask[row * 128 + chunk * 2 + 1] = (unsigned)(m >> 32);
        }
    } else {
        int i = ((blockIdx.x - 2048) * 256 + threadIdx.x) * 8;  // 524288 floats
        const float* src; int off;
        if (i < 262144) {
            const float* ws[4] = {Wq, Wk, Wv, Wo};
            src = ws[i >> 16]; off = i & 65535;
        } else if (i < 393216) { src = W1; off = i - 262144; }
        else                   { src = W2; off = i - 393216; }
        float4 a = *(const float4*)(src + off);
        float4 b = *(const float4*)(src + off + 4);
        *(s16x8*)(wout + i) = pack8(a, b);
    }
}

// ---------------------------------------------------------------------------
// QKV projection over stacked [Wq;Wk;Wv] (768 rows of Wb). Wave = 16x16 tile,
// 2 K-split acc chains. Q gets scale*log2e folded in.
__global__ __launch_bounds__(256) void qkv_kernel(const float* __restrict__ X,
                                                  const short* __restrict__ Wb,
                                                  const float* __restrict__ bq,
                                                  const float* __restrict__ bk,
                                                  const float* __restrict__ bv,
                                                  short* __restrict__ Qb,
                                                  short* __restrict__ Kb,
                                                  short* __restrict__ Vtb) {
    const int tid = threadIdx.x;
    const int wv = tid >> 6, lane = tid & 63;
    const int quad = lane >> 4, col = lane & 15;
    const int n0 = (blockIdx.x * 4 + wv) * 16;
    const int o0 = blockIdx.y * 16;                 // 0..752, z uniform per block
    const int z = o0 >> 8;
    const float* bias = (z == 0) ? bq : (z == 1 ? bk : bv);
    const float QSC = 0.25505653437397888f;         // log2e / sqrt(32)

    f32x4 acc0 = {0.f, 0.f, 0.f, 0.f}, acc1 = {0.f, 0.f, 0.f, 0.f};
    const float* ap = X + (size_t)(n0 + col) * DMODEL + quad * 8;
    const short* wp = Wb + (size_t)(o0 + col) * DMODEL + quad * 8;
#pragma unroll
    for (int k0 = 0; k0 < DMODEL; k0 += 64) {
        float4 a0 = *(const float4*)(ap + k0);
        float4 a1 = *(const float4*)(ap + k0 + 4);
        float4 a2 = *(const float4*)(ap + k0 + 32);
        float4 a3 = *(const float4*)(ap + k0 + 36);
        s16x8 b0 = *(const s16x8*)(wp + k0);
        s16x8 b1 = *(const s16x8*)(wp + k0 + 32);
        acc0 = __builtin_amdgcn_mfma_f32_16x16x32_bf16(pack8(a0, a1), b0, acc0, 0, 0, 0);
        acc1 = __builtin_amdgcn_mfma_f32_16x16x32_bf16(pack8(a2, a3), b1, acc1, 0, 0, 0);
    }
    const int o = o0 + col;
    const int oo = o & 255;
    float bvv = bias[oo];
#pragma unroll
    for (int r = 0; r < 4; ++r) {
        int n = n0 + quad * 4 + r;
        float v = acc0[r] + acc1[r] + bvv;
        if (z == 0)      Qb[(size_t)n * DMODEL + oo] = bf16r(v * QSC);
        else if (z == 1) Kb[(size_t)(oo >> 5) * NROWS * HDIM + (size_t)n * HDIM + (oo & 31)] = bf16r(v);
        else             Vtb[(size_t)oo * NROWS + n] = bf16r(v);
    }
}

// ---------------------------------------------------------------------------
// Flash attention, S^T orientation, fixed-M softmax, 32 q per wave (2 q-subtiles
// sharing K/V fragments), 8-way key split. Row-sums on the MFMA pipe (P·1).
// Outputs PARTIAL sums (fixed M -> linear): Opart[khalf], lpart[khalf].
__global__ __launch_bounds__(256) void attn_kernel(const short* __restrict__ Qb,
                                                   const short* __restrict__ Kb,
                                                   const short* __restrict__ Vtb,
                                                   const unsigned* __restrict__ mask,
                                                   float* __restrict__ Opart,
                                                   float* __restrict__ lpart) {
    __shared__ union {
        short sP[2][16 * PSTRIDE];     // 4608 B (P scratch, during K-loop)
        float sO[HDIM][OSTRIDE];       // 4224 B (merge buffer, after loop)
    } u[4];
    __shared__ float sl[4][32];

    const int tid = threadIdx.x;
    const int wv = tid >> 6, lane = tid & 63;
    const int quad = lane >> 4, col = lane & 15;
    const int khalf = blockIdx.x & 1;
    const int h = (blockIdx.x >> 1) & 7;
    const int q0 = (blockIdx.x >> 4) * 32;
    const int kw = khalf * 2048 + wv * 512;

    s16x8 qf[2];
    qf[0] = *(const s16x8*)(Qb + (size_t)(q0 + col) * DMODEL + h * HDIM + quad * 8);
    qf[1] = *(const s16x8*)(Qb + (size_t)(q0 + 16 + col) * DMODEL + h * HDIM + quad * 8);

    const short* kp  = Kb + (size_t)h * NROWS * HDIM + (size_t)(kw + col) * HDIM + quad * 8;
    const short* vp0 = Vtb + (size_t)(h * HDIM + col) * NROWS + kw + quad * 8;
    const short* vp1 = vp0 + (size_t)16 * NROWS;
    const unsigned* mp0 = mask + (size_t)(q0 + col) * 128 + (kw >> 5);
    const unsigned* mp1 = mp0 + 16 * 128;

    // ones-row A fragment: A[m][k] = (m==0) ? 1.0bf : 0
    const short onev = (col == 0) ? (short)0x3F80 : (short)0;
    const s16x8 ones = {onev, onev, onev, onev, onev, onev, onev, onev};

    f32x4 zero = {0.f, 0.f, 0.f, 0.f};
    f32x4 acc[2][2] = {{zero, zero}, {zero, zero}};
    f32x4 lacc[2] = {zero, zero};
    const f32x4 cinit = {-M2C, -M2C, -M2C, -M2C};

#pragma unroll 2
    for (int it = 0; it < 8; ++it) {
        const short* k = kp + it * 64 * HDIM;
        s16x8 kf0 = *(const s16x8*)(k);
        s16x8 kf1 = *(const s16x8*)(k + 16 * HDIM);
        s16x8 kf2 = *(const s16x8*)(k + 32 * HDIM);
        s16x8 kf3 = *(const s16x8*)(k + 48 * HDIM);
        uint2 w0 = *(const uint2*)(mp0 + it * 2);
        uint2 w1 = *(const uint2*)(mp1 + it * 2);
        const short* v0 = vp0 + it * 64;
        const short* v1 = vp1 + it * 64;
        s16x8 vf00 = *(const s16x8*)(v0);
        s16x8 vf01 = *(const s16x8*)(v0 + 32);
        s16x8 vf10 = *(const s16x8*)(v1);
        s16x8 vf11 = *(const s16x8*)(v1 + 32);

#pragma unroll
        for (int qs = 0; qs < 2; ++qs) {
            unsigned wlo = (qs ? w1.x : w0.x) >> (quad * 4);
            unsigned whi = (qs ? w1.y : w0.y) >> (quad * 4);
            f32x4 st[4];
            st[0] = __builtin_amdgcn_mfma_f32_16x16x32_bf16(kf0, qf[qs], cinit, 0, 0, 0);
            st[1] = __builtin_amdgcn_mfma_f32_16x16x32_bf16(kf1, qf[qs], cinit, 0, 0, 0);
            st[2] = __builtin_amdgcn_mfma_f32_16x16x32_bf16(kf2, qf[qs], cinit, 0, 0, 0);
            st[3] = __builtin_amdgcn_mfma_f32_16x16x32_bf16(kf3, qf[qs], cinit, 0, 0, 0);

            float p[4][4];
#pragma unroll
            for (int t = 0; t < 4; ++t) {
                unsigned wm = (t < 2) ? wlo : whi;
#pragma unroll
                for (int r = 0; r < 4; ++r) {
                    float e = fexp2(st[t][r]);
                    bool ok = (wm & (1u << ((t & 1) * 16 + r))) != 0u;
                    p[t][r] = ok ? e : 0.f;
                }
            }

            short* pb = &u[wv].sP[qs][0];
#pragma unroll
            for (int t = 0; t < 4; ++t) {
                uint2 pr;
                pr.x = pk_bf16(p[t][0], p[t][1]);
                pr.y = pk_bf16(p[t][2], p[t][3]);
                *(uint2*)(pb + col * PSTRIDE + t * 16 + quad * 4) = pr;
            }
            s16x8 pb0 = *(const s16x8*)(pb + col * PSTRIDE + quad * 8);
            s16x8 pb1 = *(const s16x8*)(pb + col * PSTRIDE + 32 + quad * 8);

            acc[qs][0] = __builtin_amdgcn_mfma_f32_16x16x32_bf16(vf00, pb0, acc[qs][0], 0, 0, 0);
            acc[qs][0] = __builtin_amdgcn_mfma_f32_16x16x32_bf16(vf01, pb1, acc[qs][0], 0, 0, 0);
            acc[qs][1] = __builtin_amdgcn_mfma_f32_16x16x32_bf16(vf10, pb0, acc[qs][1], 0, 0, 0);
            acc[qs][1] = __builtin_amdgcn_mfma_f32_16x16x32_bf16(vf11, pb1, acc[qs][1], 0, 0, 0);
            lacc[qs] = __builtin_amdgcn_mfma_f32_16x16x32_bf16(ones, pb0, lacc[qs], 0, 0, 0);
            lacc[qs] = __builtin_amdgcn_mfma_f32_16x16x32_bf16(ones, pb1, lacc[qs], 0, 0, 0);
        }
    }

    // partition partials -> LDS (sP region of this wave is dead now)
#pragma unroll
    for (int qs = 0; qs < 2; ++qs) {
        if (lane < 16) sl[wv][qs * 16 + col] = lacc[qs][0];  // D row 0
#pragma unroll
        for (int rr = 0; rr < 4; ++rr) {
            u[wv].sO[quad * 4 + rr][qs * 16 + col]      = acc[qs][0][rr];
            u[wv].sO[16 + quad * 4 + rr][qs * 16 + col] = acc[qs][1][rr];
        }
    }
    __syncthreads();

    // merge this block's 4 key-partitions; write PARTIAL sums for this khalf
    const int q = tid >> 3, hd0 = (tid & 7) * 4;
    float l = sl[0][q] + sl[1][q] + sl[2][q] + sl[3][q];
    float4 ov;
    ov.x = u[0].sO[hd0][q]     + u[1].sO[hd0][q]     + u[2].sO[hd0][q]     + u[3].sO[hd0][q];
    ov.y = u[0].sO[hd0 + 1][q] + u[1].sO[hd0 + 1][q] + u[2].sO[hd0 + 1][q] + u[3].sO[hd0 + 1][q];
    ov.z = u[0].sO[hd0 + 2][q] + u[1].sO[hd0 + 2][q] + u[2].sO[hd0 + 2][q] + u[3].sO[hd0 + 2][q];
    ov.w = u[0].sO[hd0 + 3][q] + u[1].sO[hd0 + 3][q] + u[2].sO[hd0 + 3][q] + u[3].sO[hd0 + 3][q];
    *(float4*)(Opart + (size_t)khalf * NM + (size_t)(q0 + q) * DMODEL + h * HDIM + hd0) = ov;
    if ((tid & 7) == 0) lpart[khalf * NROWS * NHEAD + (q0 + q) * NHEAD + h] = l;
}

// ---------------------------------------------------------------------------
// GEMM: wave = 16x16 tile, 2 K-split acc chains (ILP) + high TLP grids.
template<int K, bool RELU, bool B16OUT>
__device__ __forceinline__ void gemm16_body(const short* __restrict__ A,
                                            const short* __restrict__ W,
                                            const float* __restrict__ bias,
                                            float* __restrict__ Cf,
                                            short* __restrict__ Cb,
                                            int Ocols) {
    const int tid = threadIdx.x;
    const int wv = tid >> 6, lane = tid & 63;
    const int quad = lane >> 4, col = lane & 15;
    const int n0 = (blockIdx.x * 4 + wv) * 16;
    const int o0 = blockIdx.y * 16;
    f32x4 acc0 = {0.f, 0.f, 0.f, 0.f}, acc1 = {0.f, 0.f, 0.f, 0.f};
    const short* ap = A + (size_t)(n0 + col) * K + quad * 8;
    const short* wp = W + (size_t)(o0 + col) * K + quad * 8;
#pragma unroll
    for (int k0 = 0; k0 < K; k0 += 64) {
        s16x8 a0 = *(const s16x8*)(ap + k0);
        s16x8 b0 = *(const s16x8*)(wp + k0);
        s16x8 a1 = *(const s16x8*)(ap + k0 + 32);
        s16x8 b1 = *(const s16x8*)(wp + k0 + 32);
        acc0 = __builtin_amdgcn_mfma_f32_16x16x32_bf16(a0, b0, acc0, 0, 0, 0);
        acc1 = __builtin_amdgcn_mfma_f32_16x16x32_bf16(a1, b1, acc1, 0, 0, 0);
    }
    const int o = o0 + col;
    float bvv = bias[o];
#pragma unroll
    for (int r = 0; r < 4; ++r) {
        int n = n0 + quad * 4 + r;
        float v = acc0[r] + acc1[r] + bvv;
        if (RELU) v = fmaxf(v, 0.f);
        if (B16OUT) Cb[(size_t)n * Ocols + o] = bf16r(v);
        else        Cf[(size_t)n * Ocols + o] = v;
    }
}

__global__ __launch_bounds__(256) void gemm_w1(const short* __restrict__ A,
                                               const short* __restrict__ W,
                                               const float* __restrict__ bias,
                                               short* __restrict__ Cb) {
    gemm16_body<256, true, true>(A, W, bias, nullptr, Cb, 512);
}

__global__ __launch_bounds__(256) void gemm_w2(const short* __restrict__ A,
                                               const short* __restrict__ W,
                                               const float* __restrict__ bias,
                                               float* __restrict__ Cf) {
    gemm16_body<512, false, false>(A, W, bias, Cf, nullptr, 256);
}

// ---------------------------------------------------------------------------
// Wo GEMM with fused attention-partial merge + 1/l normalization in A-prep.
// Wave = 16x16 tile, 2 K-split chains (by head parity).
__global__ __launch_bounds__(256) void gemm_wo(const float* __restrict__ Opart,
                                               const float* __restrict__ lpart,
                                               const short* __restrict__ W,
                                               const float* __restrict__ bias,
                                               float* __restrict__ Cf) {
    const int tid = threadIdx.x;
    const int wv = tid >> 6, lane = tid & 63;
    const int quad = lane >> 4, col = lane & 15;
    const int n0 = (blockIdx.x * 4 + wv) * 16;
    const int o0 = blockIdx.y * 16;
    f32x4 acc0 = {0.f, 0.f, 0.f, 0.f}, acc1 = {0.f, 0.f, 0.f, 0.f};
    const int n = n0 + col;
    const float* a0p = Opart + (size_t)n * DMODEL + quad * 8;
    const float* a1p = a0p + NM;
    const float* l0p = lpart + (size_t)n * NHEAD;
    const float* l1p = l0p + NROWS * NHEAD;
    const short* wp = W + (size_t)(o0 + col) * DMODEL + quad * 8;
#pragma unroll
    for (int k0 = 0; k0 < DMODEL; k0 += 32) {
        const int head = k0 >> 5;
        float inv = 1.f / (l0p[head] + l1p[head]);   // diag allowed -> l > 0
        float4 xa = *(const float4*)(a0p + k0);
        float4 xb = *(const float4*)(a0p + k0 + 4);
        float4 ya = *(const float4*)(a1p + k0);
        float4 yb = *(const float4*)(a1p + k0 + 4);
        float4 s0, s1;
        s0.x = (xa.x + ya.x) * inv; s0.y = (xa.y + ya.y) * inv;
        s0.z = (xa.z + ya.z) * inv; s0.w = (xa.w + ya.w) * inv;
        s1.x = (xb.x + yb.x) * inv; s1.y = (xb.y + yb.y) * inv;
        s1.z = (xb.z + yb.z) * inv; s1.w = (xb.w + yb.w) * inv;
        s16x8 af = pack8(s0, s1);
        s16x8 bf = *(const s16x8*)(wp + k0);
        if (head & 1) acc1 = __builtin_amdgcn_mfma_f32_16x16x32_bf16(af, bf, acc1, 0, 0, 0);
        else          acc0 = __builtin_amdgcn_mfma_f32_16x16x32_bf16(af, bf, acc0, 0, 0, 0);
    }
    const int o = o0 + col;
    float bvv = bias[o];
#pragma unroll
    for (int r = 0; r < 4; ++r)
        Cf[(size_t)(n0 + quad * 4 + r) * DMODEL + o] = acc0[r] + acc1[r] + bvv;
}

// ---------------------------------------------------------------------------
// y = LN(a+b)*g + beta; writes f32 Y and optional bf16 Yb.
__global__ __launch_bounds__(256) void ln_kernel(const float* __restrict__ Xa,
                                                 const float* __restrict__ Xb,
                                                 const float* __restrict__ g,
                                                 const float* __restrict__ be,
                                                 float* __restrict__ Y,
                                                 short* __restrict__ Yb) {
    const int wv = threadIdx.x >> 6, lane = threadIdx.x & 63;
    const int row = blockIdx.x * 4 + wv;
    const float4 av = *(const float4*)(Xa + (size_t)row * DMODEL + lane * 4);
    const float4 bv = *(const float4*)(Xb + (size_t)row * DMODEL + lane * 4);
    float v0 = av.x + bv.x, v1 = av.y + bv.y, v2 = av.z + bv.z, v3 = av.w + bv.w;
    float s = v0 + v1 + v2 + v3;
#pragma unroll
    for (int m = 1; m < 64; m <<= 1) s += __shfl_xor(s, m, 64);
    float mean = s * (1.f / 256.f);
    float d0 = v0 - mean, d1 = v1 - mean, d2 = v2 - mean, d3 = v3 - mean;
    float q = d0 * d0 + d1 * d1 + d2 * d2 + d3 * d3;
#pragma unroll
    for (int m = 1; m < 64; m <<= 1) q += __shfl_xor(q, m, 64);
    float rstd = rsqrtf(q * (1.f / 256.f) + 1e-5f);
    const float4 gv  = *(const float4*)(g + lane * 4);
    const float4 bev = *(const float4*)(be + lane * 4);
    float4 y;
    y.x = d0 * rstd * gv.x + bev.x;
    y.y = d1 * rstd * gv.y + bev.y;
    y.z = d2 * rstd * gv.z + bev.z;
    y.w = d3 * rstd * gv.w + bev.w;
    *(float4*)(Y + (size_t)row * DMODEL + lane * 4) = y;
    if (Yb) {
        uint2 yb;
        yb.x = pk_bf16(y.x, y.y);
        yb.y = pk_bf16(y.z, y.w);
        *(uint2*)(Yb + (size_t)row * DMODEL + lane * 4) = yb;
    }
}

// ---------------------------------------------------------------------------
extern "C" void kernel_launch(void* const* d_in, const int* in_sizes, int n_in,
                              void* d_out, int out_size, void* d_ws, size_t ws_size,
                              hipStream_t stream) {
    const float* x   = (const float*)d_in[0];
    const int*   adj = (const int*)d_in[1];
    const float* Wq  = (const float*)d_in[2];
    const float* Wk  = (const float*)d_in[3];
    const float* Wv  = (const float*)d_in[4];
    const float* bq  = (const float*)d_in[5];
    const float* bk  = (const float*)d_in[6];
    const float* bv  = (const float*)d_in[7];
    const float* Wo  = (const float*)d_in[8];
    const float* bo  = (const float*)d_in[9];
    const float* g1  = (const float*)d_in[10];
    const float* be1 = (const float*)d_in[11];
    const float* W1  = (const float*)d_in[12];
    const float* b1  = (const float*)d_in[13];
    const float* W2  = (const float*)d_in[14];
    const float* b2  = (const float*)d_in[15];
    const float* g2  = (const float*)d_in[16];
    const float* be2 = (const float*)d_in[17];
    float* out = (float*)d_out;

    char* p = (char*)d_ws;
    unsigned* mask = (unsigned*)p; p += (size_t)NROWS * 128 * 4;          //  2 MB
    short* Wb    = (short*)p;      p += (size_t)524288 * 2;               //  1 MB
    short* Qb    = (short*)p;      p += (size_t)NM * 2;                   //  2 MB
    short* Kb    = (short*)p;      p += (size_t)NM * 2;                   //  2 MB
    short* Vtb   = (short*)p;      p += (size_t)NM * 2;                   //  2 MB
    float* Opart = (float*)p;      p += (size_t)2 * NM * 4;               //  8 MB
    float* lpart = (float*)p;      p += (size_t)2 * NROWS * NHEAD * 4;    // .25 MB
    float* hbuf  = (float*)p;      p += (size_t)NM * 4;                   //  4 MB
    float* y1    = (float*)p;      p += (size_t)NM * 4;                   //  4 MB
    short* y1b   = (short*)p;      p += (size_t)NM * 2;                   //  2 MB
    short* rbuf  = (short*)p;      p += (size_t)NROWS * 512 * 2;          //  4 MB
    float* t2    = Opart;          // alias: Opart dead after gemm_wo

    prep_kernel<<<dim3(2304), dim3(256), 0, stream>>>(adj, mask, Wq, Wk, Wv, Wo, W1, W2, Wb);
    qkv_kernel<<<dim3(64, 48), dim3(256), 0, stream>>>(x, Wb, bq, bk, bv, Qb, Kb, Vtb);
    attn_kernel<<<dim3(2048), dim3(256), 0, stream>>>(Qb, Kb, Vtb, mask, Opart, lpart);
    gemm_wo<<<dim3(64, 16), dim3(256), 0, stream>>>(Opart, lpart, Wb + 196608, bo, hbuf);
    ln_kernel<<<dim3(1024), dim3(256), 0, stream>>>(x, hbuf, g1, be1, y1, y1b);
    gemm_w1<<<dim3(64, 32), dim3(256), 0, stream>>>(y1b, Wb + 262144, b1, rbuf);
    gemm_w2<<<dim3(64, 16), dim3(256), 0, stream>>>(rbuf, Wb + 393216, b2, t2);
    ln_kernel<<<dim3(1024), dim3(256), 0, stream>>>(y1, t2, g2, be2, out, nullptr);
}

// Round 8
// 240.767 us; speedup vs baseline: 1.1999x; 1.1999x over previous
//
#include <hip/hip_runtime.h>
#include <hip/hip_bf16.h>

typedef __attribute__((ext_vector_type(4))) float f32x4;
typedef __attribute__((ext_vector_type(8))) short s16x8;

#define NROWS 4096
#define DMODEL 256
#define NHEAD 8
#define HDIM 32
#define PSTRIDE 72     // attn P-scratch row: 144 B, 16B-aligned
#define OSTRIDE 33     // attn sO row
#define M2C 24.0f      // fixed softmax max (log2 domain)
#define NM (NROWS * DMODEL)
// mega-kernel LDS strides
#define SA_S 264       // shorts/row (528 B, 16B-aligned)
#define SH_S 268       // f32/row (1072 B, 16B-aligned)
#define SY_S 264       // shorts/row
#define SR_S 520       // shorts/row (1040 B, 16B-aligned)

__device__ __forceinline__ short bf16r(float f) {
    union { float f; unsigned u; } v; v.f = f;
    unsigned r = v.u + 0x7fffu + ((v.u >> 16) & 1u);  // RNE
    return (short)(r >> 16);
}

__device__ __forceinline__ float fexp2(float x) {
    float r;
    asm("v_exp_f32 %0, %1" : "=v"(r) : "v"(x));
    return r;
}

__device__ __forceinline__ unsigned pk_bf16(float a, float b) {
#if __has_builtin(__builtin_amdgcn_cvt_pk_bf16_f32)
    typedef __bf16 bf2 __attribute__((ext_vector_type(2)));
    union { bf2 h; unsigned u; } c;
    c.h = __builtin_amdgcn_cvt_pk_bf16_f32(a, b);
    return c.u;
#else
    return (unsigned)(unsigned short)bf16r(a) | ((unsigned)(unsigned short)bf16r(b) << 16);
#endif
}

__device__ __forceinline__ s16x8 pack8(float4 a, float4 b) {
    s16x8 r;
    r[0] = bf16r(a.x); r[1] = bf16r(a.y); r[2] = bf16r(a.z); r[3] = bf16r(a.w);
    r[4] = bf16r(b.x); r[5] = bf16r(b.y); r[6] = bf16r(b.z); r[7] = bf16r(b.w);
    return r;
}

// ---------------------------------------------------------------------------
// Dispatch 1 (fused): blocks [0,768): QKV GEMM (f32 weights, inline pack).
// [768,2816): adj -> bitmask (diag OR'd), 32 wave-tasks each.
// [2816,2976): pack Wo/W1/W2 to bf16 into Wb.
__global__ __launch_bounds__(256) void qkvprep_kernel(
        const float* __restrict__ X,
        const float* __restrict__ Wq, const float* __restrict__ Wk,
        const float* __restrict__ Wv,
        const float* __restrict__ bq, const float* __restrict__ bk,
        const float* __restrict__ bv,
        const int* __restrict__ adj, unsigned* __restrict__ mask,
        const float* __restrict__ Wo, const float* __restrict__ W1,
        const float* __restrict__ W2, short* __restrict__ Wb,
        short* __restrict__ Qb, short* __restrict__ Kb,
        short* __restrict__ Vtb) {
    const int b = blockIdx.x;
    const int tid = threadIdx.x;
    const int lane = tid & 63;
    if (b < 768) {
        // ---- QKV GEMM: wave = 16 rows x 64 cols, 4 acc chains ----
        const int wv = tid >> 6;
        const int quad = lane >> 4, col = lane & 15;
        const int bx = b & 63, by = b >> 6;           // by 0..11
        const int o0 = by * 64;                        // 0..704
        const int z = o0 >> 8;
        const float* Wsrc = (z == 0) ? Wq : (z == 1 ? Wk : Wv);
        const float* bias = (z == 0) ? bq : (z == 1 ? bk : bv);
        const int ow0 = o0 & 255;
        const int n0 = bx * 64 + wv * 16;
        const float QSC = 0.25505653437397888f;        // log2e / sqrt(32)

        f32x4 zero = {0.f, 0.f, 0.f, 0.f};
        f32x4 acc[4] = {zero, zero, zero, zero};
        const float* ap = X + (size_t)(n0 + col) * DMODEL + quad * 8;
#pragma unroll
        for (int k0 = 0; k0 < DMODEL; k0 += 32) {
            float4 a0 = *(const float4*)(ap + k0);
            float4 a1 = *(const float4*)(ap + k0 + 4);
            s16x8 af = pack8(a0, a1);
#pragma unroll
            for (int t = 0; t < 4; ++t) {
                const float* wp = Wsrc + (size_t)(ow0 + t * 16 + col) * DMODEL + quad * 8 + k0;
                s16x8 bf = pack8(*(const float4*)wp, *(const float4*)(wp + 4));
                acc[t] = __builtin_amdgcn_mfma_f32_16x16x32_bf16(af, bf, acc[t], 0, 0, 0);
            }
        }
#pragma unroll
        for (int t = 0; t < 4; ++t) {
            const int oo = ow0 + t * 16 + col;
            float bvv = bias[oo];
#pragma unroll
            for (int r = 0; r < 4; ++r) {
                int n = n0 + quad * 4 + r;
                float v = acc[t][r] + bvv;
                if (z == 0)      Qb[(size_t)n * DMODEL + oo] = bf16r(v * QSC);
                else if (z == 1) Kb[(size_t)(oo >> 5) * NROWS * HDIM + (size_t)n * HDIM + (oo & 31)] = bf16r(v);
                else             Vtb[(size_t)oo * NROWS + n] = bf16r(v);
            }
        }
    } else if (b < 2816) {
        // ---- adj -> bitmask ----
        const int waveid = (b - 768) * 4 + (tid >> 6);  // 0..8191
#pragma unroll
        for (int i = 0; i < 32; ++i) {
            const int task = waveid + i * 8192;          // 0..262143
            const int row = task >> 6, chunk = task & 63;
            const int c = chunk * 64 + lane;
            int a = adj[(size_t)row * NROWS + c];
            unsigned long long m = __ballot(a > 0 || c == row);
            if (lane == 0)      mask[row * 128 + chunk * 2]     = (unsigned)m;
            else if (lane == 1) mask[row * 128 + chunk * 2 + 1] = (unsigned)(m >> 32);
        }
    } else {
        // ---- pack Wo/W1/W2 (327680 floats) ----
        int i = (b - 2816) * 2048 + tid * 8;
        const float* src; int off;
        if (i < 65536)       { src = Wo; off = i; }
        else if (i < 196608) { src = W1; off = i - 65536; }
        else                 { src = W2; off = i - 196608; }
        float4 a = *(const float4*)(src + off);
        float4 c = *(const float4*)(src + off + 4);
        *(s16x8*)(Wb + i) = pack8(a, c);
    }
}

// ---------------------------------------------------------------------------
// Dispatch 2: flash attention (round-7 kernel, unchanged).
__global__ __launch_bounds__(256) void attn_kernel(const short* __restrict__ Qb,
                                                   const short* __restrict__ Kb,
                                                   const short* __restrict__ Vtb,
                                                   const unsigned* __restrict__ mask,
                                                   float* __restrict__ Opart,
                                                   float* __restrict__ lpart) {
    __shared__ union {
        short sP[2][16 * PSTRIDE];
        float sO[HDIM][OSTRIDE];
    } u[4];
    __shared__ float sl[4][32];

    const int tid = threadIdx.x;
    const int wv = tid >> 6, lane = tid & 63;
    const int quad = lane >> 4, col = lane & 15;
    const int khalf = blockIdx.x & 1;
    const int h = (blockIdx.x >> 1) & 7;
    const int q0 = (blockIdx.x >> 4) * 32;
    const int kw = khalf * 2048 + wv * 512;

    s16x8 qf[2];
    qf[0] = *(const s16x8*)(Qb + (size_t)(q0 + col) * DMODEL + h * HDIM + quad * 8);
    qf[1] = *(const s16x8*)(Qb + (size_t)(q0 + 16 + col) * DMODEL + h * HDIM + quad * 8);

    const short* kp  = Kb + (size_t)h * NROWS * HDIM + (size_t)(kw + col) * HDIM + quad * 8;
    const short* vp0 = Vtb + (size_t)(h * HDIM + col) * NROWS + kw + quad * 8;
    const short* vp1 = vp0 + (size_t)16 * NROWS;
    const unsigned* mp0 = mask + (size_t)(q0 + col) * 128 + (kw >> 5);
    const unsigned* mp1 = mp0 + 16 * 128;

    const short onev = (col == 0) ? (short)0x3F80 : (short)0;
    const s16x8 ones = {onev, onev, onev, onev, onev, onev, onev, onev};

    f32x4 zero = {0.f, 0.f, 0.f, 0.f};
    f32x4 acc[2][2] = {{zero, zero}, {zero, zero}};
    f32x4 lacc[2] = {zero, zero};
    const f32x4 cinit = {-M2C, -M2C, -M2C, -M2C};

#pragma unroll 2
    for (int it = 0; it < 8; ++it) {
        const short* k = kp + it * 64 * HDIM;
        s16x8 kf0 = *(const s16x8*)(k);
        s16x8 kf1 = *(const s16x8*)(k + 16 * HDIM);
        s16x8 kf2 = *(const s16x8*)(k + 32 * HDIM);
        s16x8 kf3 = *(const s16x8*)(k + 48 * HDIM);
        uint2 w0 = *(const uint2*)(mp0 + it * 2);
        uint2 w1 = *(const uint2*)(mp1 + it * 2);
        const short* v0 = vp0 + it * 64;
        const short* v1 = vp1 + it * 64;
        s16x8 vf00 = *(const s16x8*)(v0);
        s16x8 vf01 = *(const s16x8*)(v0 + 32);
        s16x8 vf10 = *(const s16x8*)(v1);
        s16x8 vf11 = *(const s16x8*)(v1 + 32);

#pragma unroll
        for (int qs = 0; qs < 2; ++qs) {
            unsigned wlo = (qs ? w1.x : w0.x) >> (quad * 4);
            unsigned whi = (qs ? w1.y : w0.y) >> (quad * 4);
            f32x4 st[4];
            st[0] = __builtin_amdgcn_mfma_f32_16x16x32_bf16(kf0, qf[qs], cinit, 0, 0, 0);
            st[1] = __builtin_amdgcn_mfma_f32_16x16x32_bf16(kf1, qf[qs], cinit, 0, 0, 0);
            st[2] = __builtin_amdgcn_mfma_f32_16x16x32_bf16(kf2, qf[qs], cinit, 0, 0, 0);
            st[3] = __builtin_amdgcn_mfma_f32_16x16x32_bf16(kf3, qf[qs], cinit, 0, 0, 0);

            float p[4][4];
#pragma unroll
            for (int t = 0; t < 4; ++t) {
                unsigned wm = (t < 2) ? wlo : whi;
#pragma unroll
                for (int r = 0; r < 4; ++r) {
                    float e = fexp2(st[t][r]);
                    bool ok = (wm & (1u << ((t & 1) * 16 + r))) != 0u;
                    p[t][r] = ok ? e : 0.f;
                }
            }

            short* pb = &u[wv].sP[qs][0];
#pragma unroll
            for (int t = 0; t < 4; ++t) {
                uint2 pr;
                pr.x = pk_bf16(p[t][0], p[t][1]);
                pr.y = pk_bf16(p[t][2], p[t][3]);
                *(uint2*)(pb + col * PSTRIDE + t * 16 + quad * 4) = pr;
            }
            s16x8 pb0 = *(const s16x8*)(pb + col * PSTRIDE + quad * 8);
            s16x8 pb1 = *(const s16x8*)(pb + col * PSTRIDE + 32 + quad * 8);

            acc[qs][0] = __builtin_amdgcn_mfma_f32_16x16x32_bf16(vf00, pb0, acc[qs][0], 0, 0, 0);
            acc[qs][0] = __builtin_amdgcn_mfma_f32_16x16x32_bf16(vf01, pb1, acc[qs][0], 0, 0, 0);
            acc[qs][1] = __builtin_amdgcn_mfma_f32_16x16x32_bf16(vf10, pb0, acc[qs][1], 0, 0, 0);
            acc[qs][1] = __builtin_amdgcn_mfma_f32_16x16x32_bf16(vf11, pb1, acc[qs][1], 0, 0, 0);
            lacc[qs] = __builtin_amdgcn_mfma_f32_16x16x32_bf16(ones, pb0, lacc[qs], 0, 0, 0);
            lacc[qs] = __builtin_amdgcn_mfma_f32_16x16x32_bf16(ones, pb1, lacc[qs], 0, 0, 0);
        }
    }

#pragma unroll
    for (int qs = 0; qs < 2; ++qs) {
        if (lane < 16) sl[wv][qs * 16 + col] = lacc[qs][0];
#pragma unroll
        for (int rr = 0; rr < 4; ++rr) {
            u[wv].sO[quad * 4 + rr][qs * 16 + col]      = acc[qs][0][rr];
            u[wv].sO[16 + quad * 4 + rr][qs * 16 + col] = acc[qs][1][rr];
        }
    }
    __syncthreads();

    const int q = tid >> 3, hd0 = (tid & 7) * 4;
    float l = sl[0][q] + sl[1][q] + sl[2][q] + sl[3][q];
    float4 ov;
    ov.x = u[0].sO[hd0][q]     + u[1].sO[hd0][q]     + u[2].sO[hd0][q]     + u[3].sO[hd0][q];
    ov.y = u[0].sO[hd0 + 1][q] + u[1].sO[hd0 + 1][q] + u[2].sO[hd0 + 1][q] + u[3].sO[hd0 + 1][q];
    ov.z = u[0].sO[hd0 + 2][q] + u[1].sO[hd0 + 2][q] + u[2].sO[hd0 + 2][q] + u[3].sO[hd0 + 2][q];
    ov.w = u[0].sO[hd0 + 3][q] + u[1].sO[hd0 + 3][q] + u[2].sO[hd0 + 3][q] + u[3].sO[hd0 + 3][q];
    *(float4*)(Opart + (size_t)khalf * NM + (size_t)(q0 + q) * DMODEL + h * HDIM + hd0) = ov;
    if ((tid & 7) == 0) lpart[khalf * NROWS * NHEAD + (q0 + q) * NHEAD + h] = l;
}

// ---------------------------------------------------------------------------
// Dispatch 3: everything after attention, per 16-row stripe (row-local chain):
// merge/normalize O -> Wo-GEMM -> LN1 -> W1+ReLU -> W2 -> LN2 -> out.
__global__ __launch_bounds__(256) void mega_kernel(
        const float* __restrict__ Opart, const float* __restrict__ lpart,
        const float* __restrict__ X,
        const short* __restrict__ Wob, const short* __restrict__ W1b,
        const short* __restrict__ W2b,
        const float* __restrict__ bo,
        const float* __restrict__ g1, const float* __restrict__ be1,
        const float* __restrict__ b1, const float* __restrict__ b2,
        const float* __restrict__ g2, const float* __restrict__ be2,
        float* __restrict__ out) {
    __shared__ union { short sA[16 * SA_S]; short sR[16 * SR_S]; } uu;  // 16640 B
    __shared__ float sH[16 * SH_S];                                     // 17152 B
    __shared__ short sY[16 * SY_S];                                     //  8448 B

    const int tid = threadIdx.x;
    const int wv = tid >> 6, lane = tid & 63;
    const int quad = lane >> 4, col = lane & 15;
    const int n0 = blockIdx.x * 16;
    const int rr_ = tid >> 4, cg = tid & 15;   // LN-phase thread map
    const int n_ln = n0 + rr_;
    f32x4 zero = {0.f, 0.f, 0.f, 0.f};

    // ---- Stage A: normalized merged O -> sA (bf16) ----
    {
        const int head = cg >> 1;
        float li = 1.f / (lpart[(size_t)n_ln * NHEAD + head] +
                          lpart[(size_t)NROWS * NHEAD + (size_t)n_ln * NHEAD + head]);
        const float* p0 = Opart + (size_t)n_ln * DMODEL + cg * 16;
        const float* p1 = p0 + NM;
        short* dst = &uu.sA[rr_ * SA_S + cg * 16];
#pragma unroll
        for (int j = 0; j < 4; ++j) {
            float4 a = ((const float4*)p0)[j];
            float4 b = ((const float4*)p1)[j];
            uint2 w;
            w.x = pk_bf16((a.x + b.x) * li, (a.y + b.y) * li);
            w.y = pk_bf16((a.z + b.z) * li, (a.w + b.w) * li);
            *(uint2*)(dst + j * 4) = w;
        }
    }
    __syncthreads();

    // ---- Stage A2: h = Anorm · Wo^T + bo (wave: 16 x 64) ----
    {
        const int o0 = wv * 64;
        f32x4 acc[4] = {zero, zero, zero, zero};
#pragma unroll
        for (int k0 = 0; k0 < DMODEL; k0 += 32) {
            s16x8 af = *(const s16x8*)&uu.sA[col * SA_S + k0 + quad * 8];
#pragma unroll
            for (int t = 0; t < 4; ++t) {
                s16x8 bf = *(const s16x8*)(Wob + (size_t)(o0 + t * 16 + col) * DMODEL + k0 + quad * 8);
                acc[t] = __builtin_amdgcn_mfma_f32_16x16x32_bf16(af, bf, acc[t], 0, 0, 0);
            }
        }
#pragma unroll
        for (int t = 0; t < 4; ++t) {
            int o = o0 + t * 16 + col;
            float bv = bo[o];
#pragma unroll
            for (int r = 0; r < 4; ++r)
                sH[(quad * 4 + r) * SH_S + o] = acc[t][r] + bv;
        }
    }
    __syncthreads();

    // ---- LN1: y1 = LN(x + h); y1 f32 in regs, bf16 -> sY ----
    float y1v[16];
    {
        const float* xp = X + (size_t)n_ln * DMODEL + cg * 16;
        float v[16];
        float s = 0.f;
#pragma unroll
        for (int j = 0; j < 4; ++j) {
            float4 xv = ((const float4*)xp)[j];
            float4 hv = *(const float4*)&sH[rr_ * SH_S + cg * 16 + j * 4];
            v[j * 4 + 0] = xv.x + hv.x; v[j * 4 + 1] = xv.y + hv.y;
            v[j * 4 + 2] = xv.z + hv.z; v[j * 4 + 3] = xv.w + hv.w;
            s += v[j * 4] + v[j * 4 + 1] + v[j * 4 + 2] + v[j * 4 + 3];
        }
#pragma unroll
        for (int m = 1; m < 16; m <<= 1) s += __shfl_xor(s, m, 64);
        float mean = s * (1.f / 256.f);
        float q = 0.f;
#pragma unroll
        for (int i = 0; i < 16; ++i) { v[i] -= mean; q += v[i] * v[i]; }
#pragma unroll
        for (int m = 1; m < 16; m <<= 1) q += __shfl_xor(q, m, 64);
        float rstd = rsqrtf(q * (1.f / 256.f) + 1e-5f);
        const float* gp = g1 + cg * 16;
        const float* bp = be1 + cg * 16;
        short* dst = &sY[rr_ * SY_S + cg * 16];
#pragma unroll
        for (int j = 0; j < 4; ++j) {
            float4 gv = ((const float4*)gp)[j];
            float4 bev = ((const float4*)bp)[j];
            float a0 = v[j * 4 + 0] * rstd * gv.x + bev.x;
            float a1 = v[j * 4 + 1] * rstd * gv.y + bev.y;
            float a2 = v[j * 4 + 2] * rstd * gv.z + bev.z;
            float a3 = v[j * 4 + 3] * rstd * gv.w + bev.w;
            y1v[j * 4 + 0] = a0; y1v[j * 4 + 1] = a1;
            y1v[j * 4 + 2] = a2; y1v[j * 4 + 3] = a3;
            uint2 w;
            w.x = pk_bf16(a0, a1);
            w.y = pk_bf16(a2, a3);
            *(uint2*)(dst + j * 4) = w;
        }
    }
    __syncthreads();

    // ---- Stage B: relu(y1 · W1^T + b1) -> sR (wave: 16 x 128) ----
    {
        const int o0 = wv * 128;
        f32x4 acc[8] = {zero, zero, zero, zero, zero, zero, zero, zero};
#pragma unroll
        for (int k0 = 0; k0 < DMODEL; k0 += 32) {
            s16x8 af = *(const s16x8*)&sY[col * SY_S + k0 + quad * 8];
#pragma unroll
            for (int t = 0; t < 8; ++t) {
                s16x8 bf = *(const s16x8*)(W1b + (size_t)(o0 + t * 16 + col) * DMODEL + k0 + quad * 8);
                acc[t] = __builtin_amdgcn_mfma_f32_16x16x32_bf16(af, bf, acc[t], 0, 0, 0);
            }
        }
#pragma unroll
        for (int t = 0; t < 8; ++t) {
            int o = o0 + t * 16 + col;
            float bv = b1[o];
#pragma unroll
            for (int r = 0; r < 4; ++r)
                uu.sR[(quad * 4 + r) * SR_S + o] = bf16r(fmaxf(acc[t][r] + bv, 0.f));
        }
    }
    __syncthreads();

    // ---- Stage C: t2 = r · W2^T + b2 (wave: 16 x 64, K=512) -> sH ----
    {
        const int o0 = wv * 64;
        f32x4 acc[4] = {zero, zero, zero, zero};
#pragma unroll
        for (int k0 = 0; k0 < 512; k0 += 32) {
            s16x8 af = *(const s16x8*)&uu.sR[col * SR_S + k0 + quad * 8];
#pragma unroll
            for (int t = 0; t < 4; ++t) {
                s16x8 bf = *(const s16x8*)(W2b + (size_t)(o0 + t * 16 + col) * 512 + k0 + quad * 8);
                acc[t] = __builtin_amdgcn_mfma_f32_16x16x32_bf16(af, bf, acc[t], 0, 0, 0);
            }
        }
#pragma unroll
        for (int t = 0; t < 4; ++t) {
            int o = o0 + t * 16 + col;
            float bv = b2[o];
#pragma unroll
            for (int r = 0; r < 4; ++r)
                sH[(quad * 4 + r) * SH_S + o] = acc[t][r] + bv;
        }
    }
    __syncthreads();

    // ---- LN2: out = LN(y1 + t2) ----
    {
        float v[16];
        float s = 0.f;
#pragma unroll
        for (int j = 0; j < 4; ++j) {
            float4 hv = *(const float4*)&sH[rr_ * SH_S + cg * 16 + j * 4];
            v[j * 4 + 0] = y1v[j * 4 + 0] + hv.x; v[j * 4 + 1] = y1v[j * 4 + 1] + hv.y;
            v[j * 4 + 2] = y1v[j * 4 + 2] + hv.z; v[j * 4 + 3] = y1v[j * 4 + 3] + hv.w;
            s += v[j * 4] + v[j * 4 + 1] + v[j * 4 + 2] + v[j * 4 + 3];
        }
#pragma unroll
        for (int m = 1; m < 16; m <<= 1) s += __shfl_xor(s, m, 64);
        float mean = s * (1.f / 256.f);
        float q = 0.f;
#pragma unroll
        for (int i = 0; i < 16; ++i) { v[i] -= mean; q += v[i] * v[i]; }
#pragma unroll
        for (int m = 1; m < 16; m <<= 1) q += __shfl_xor(q, m, 64);
        float rstd = rsqrtf(q * (1.f / 256.f) + 1e-5f);
        const float* gp = g2 + cg * 16;
        const float* bp = be2 + cg * 16;
        float* op = out + (size_t)n_ln * DMODEL + cg * 16;
#pragma unroll
        for (int j = 0; j < 4; ++j) {
            float4 gv = ((const float4*)gp)[j];
            float4 bev = ((const float4*)bp)[j];
            float4 y;
            y.x = v[j * 4 + 0] * rstd * gv.x + bev.x;
            y.y = v[j * 4 + 1] * rstd * gv.y + bev.y;
            y.z = v[j * 4 + 2] * rstd * gv.z + bev.z;
            y.w = v[j * 4 + 3] * rstd * gv.w + bev.w;
            ((float4*)op)[j] = y;
        }
    }
}

// ---------------------------------------------------------------------------
extern "C" void kernel_launch(void* const* d_in, const int* in_sizes, int n_in,
                              void* d_out, int out_size, void* d_ws, size_t ws_size,
                              hipStream_t stream) {
    const float* x   = (const float*)d_in[0];
    const int*   adj = (const int*)d_in[1];
    const float* Wq  = (const float*)d_in[2];
    const float* Wk  = (const float*)d_in[3];
    const float* Wv  = (const float*)d_in[4];
    const float* bq  = (const float*)d_in[5];
    const float* bk  = (const float*)d_in[6];
    const float* bv  = (const float*)d_in[7];
    const float* Wo  = (const float*)d_in[8];
    const float* bo  = (const float*)d_in[9];
    const float* g1  = (const float*)d_in[10];
    const float* be1 = (const float*)d_in[11];
    const float* W1  = (const float*)d_in[12];
    const float* b1  = (const float*)d_in[13];
    const float* W2  = (const float*)d_in[14];
    const float* b2  = (const float*)d_in[15];
    const float* g2  = (const float*)d_in[16];
    const float* be2 = (const float*)d_in[17];
    float* out = (float*)d_out;

    char* p = (char*)d_ws;
    unsigned* mask = (unsigned*)p; p += (size_t)NROWS * 128 * 4;          //  2 MB
    short* Wb    = (short*)p;      p += (size_t)327680 * 2;               // .64 MB
    short* Qb    = (short*)p;      p += (size_t)NM * 2;                   //  2 MB
    short* Kb    = (short*)p;      p += (size_t)NM * 2;                   //  2 MB
    short* Vtb   = (short*)p;      p += (size_t)NM * 2;                   //  2 MB
    float* Opart = (float*)p;      p += (size_t)2 * NM * 4;               //  8 MB
    float* lpart = (float*)p;      p += (size_t)2 * NROWS * NHEAD * 4;    // .25 MB

    qkvprep_kernel<<<dim3(2976), dim3(256), 0, stream>>>(
        x, Wq, Wk, Wv, bq, bk, bv, adj, mask, Wo, W1, W2, Wb, Qb, Kb, Vtb);
    attn_kernel<<<dim3(2048), dim3(256), 0, stream>>>(Qb, Kb, Vtb, mask, Opart, lpart);
    mega_kernel<<<dim3(256), dim3(256), 0, stream>>>(
        Opart, lpart, x, Wb, Wb + 65536, Wb + 196608,
        bo, g1, be1, b1, b2, g2, be2, out);
}

// Round 10
// 237.469 us; speedup vs baseline: 1.2166x; 1.0139x over previous
//
#include <hip/hip_runtime.h>
#include <hip/hip_bf16.h>

typedef __attribute__((ext_vector_type(4))) float f32x4;
typedef __attribute__((ext_vector_type(8))) short s16x8;

#define NROWS 4096
#define DMODEL 256
#define NHEAD 8
#define HDIM 32
#define PSTRIDE 72     // attn P-scratch row: 144 B, 16B-aligned
#define OSTRIDE 33     // attn sO row
#define M2C 24.0f      // fixed softmax max (log2 domain)
#define NM (NROWS * DMODEL)
// mega-kernel LDS strides
#define SA_S 264
#define SH_S 268
#define SY_S 264
#define SR_S 520

__device__ __forceinline__ short bf16r(float f) {
    union { float f; unsigned u; } v; v.f = f;
    unsigned r = v.u + 0x7fffu + ((v.u >> 16) & 1u);  // RNE
    return (short)(r >> 16);
}

__device__ __forceinline__ float fexp2(float x) {
    float r;
    asm("v_exp_f32 %0, %1" : "=v"(r) : "v"(x));
    return r;
}

__device__ __forceinline__ unsigned pk_bf16(float a, float b) {
#if __has_builtin(__builtin_amdgcn_cvt_pk_bf16_f32)
    typedef __bf16 bf2 __attribute__((ext_vector_type(2)));
    union { bf2 h; unsigned u; } c;
    c.h = __builtin_amdgcn_cvt_pk_bf16_f32(a, b);
    return c.u;
#else
    return (unsigned)(unsigned short)bf16r(a) | ((unsigned)(unsigned short)bf16r(b) << 16);
#endif
}

__device__ __forceinline__ s16x8 pack8(float4 a, float4 b) {
    s16x8 r;
    r[0] = bf16r(a.x); r[1] = bf16r(a.y); r[2] = bf16r(a.z); r[3] = bf16r(a.w);
    r[4] = bf16r(b.x); r[5] = bf16r(b.y); r[6] = bf16r(b.z); r[7] = bf16r(b.w);
    return r;
}

// ---------------------------------------------------------------------------
// Dispatch 1 (fused): blocks [0,768): QKV GEMM (f32 weights, inline pack).
// [768,2816): adj -> bitmask via int4 loads + nibble/shuffle pack.
// [2816,2976): pack Wo/W1/W2 to bf16 into Wb.
__global__ __launch_bounds__(256) void qkvprep_kernel(
        const float* __restrict__ X,
        const float* __restrict__ Wq, const float* __restrict__ Wk,
        const float* __restrict__ Wv,
        const float* __restrict__ bq, const float* __restrict__ bk,
        const float* __restrict__ bv,
        const int* __restrict__ adj, unsigned* __restrict__ mask,
        const float* __restrict__ Wo, const float* __restrict__ W1,
        const float* __restrict__ W2, short* __restrict__ Wb,
        short* __restrict__ Qb, short* __restrict__ Kb,
        short* __restrict__ Vtb) {
    const int b = blockIdx.x;
    const int tid = threadIdx.x;
    const int lane = tid & 63;
    if (b < 768) {
        // ---- QKV GEMM: wave = 16 rows x 64 cols, 4 acc chains ----
        const int wv = tid >> 6;
        const int quad = lane >> 4, col = lane & 15;
        const int bx = b & 63, by = b >> 6;           // by 0..11
        const int o0 = by * 64;                        // 0..704
        const int z = o0 >> 8;
        const float* Wsrc = (z == 0) ? Wq : (z == 1 ? Wk : Wv);
        const float* bias = (z == 0) ? bq : (z == 1 ? bk : bv);
        const int ow0 = o0 & 255;
        const int n0 = bx * 64 + wv * 16;
        const float QSC = 0.25505653437397888f;        // log2e / sqrt(32)

        f32x4 zero = {0.f, 0.f, 0.f, 0.f};
        f32x4 acc[4] = {zero, zero, zero, zero};
        const float* ap = X + (size_t)(n0 + col) * DMODEL + quad * 8;
#pragma unroll
        for (int k0 = 0; k0 < DMODEL; k0 += 32) {
            float4 a0 = *(const float4*)(ap + k0);
            float4 a1 = *(const float4*)(ap + k0 + 4);
            s16x8 af = pack8(a0, a1);
#pragma unroll
            for (int t = 0; t < 4; ++t) {
                const float* wp = Wsrc + (size_t)(ow0 + t * 16 + col) * DMODEL + quad * 8 + k0;
                s16x8 bf = pack8(*(const float4*)wp, *(const float4*)(wp + 4));
                acc[t] = __builtin_amdgcn_mfma_f32_16x16x32_bf16(af, bf, acc[t], 0, 0, 0);
            }
        }
#pragma unroll
        for (int t = 0; t < 4; ++t) {
            const int oo = ow0 + t * 16 + col;
            float bvv = bias[oo];
#pragma unroll
            for (int r = 0; r < 4; ++r) {
                int n = n0 + quad * 4 + r;
                float v = acc[t][r] + bvv;
                if (z == 0)      Qb[(size_t)n * DMODEL + oo] = bf16r(v * QSC);
                else if (z == 1) Kb[(size_t)(oo >> 5) * NROWS * HDIM + (size_t)n * HDIM + (oo & 31)] = bf16r(v);
                else             Vtb[(size_t)oo * NROWS + n] = bf16r(v);
            }
        }
    } else if (b < 2816) {
        // ---- adj -> bitmask: task = (row, 256-col segment); 65536 tasks ----
        const int waveid = (b - 768) * 4 + (tid >> 6);  // 0..8191
        int4 av[8];
        int rows[8], segs[8];
#pragma unroll
        for (int i = 0; i < 8; ++i) {
            const int task = waveid + i * 8192;          // 0..65535
            rows[i] = task >> 4; segs[i] = task & 15;
            av[i] = *(const int4*)(adj + (size_t)rows[i] * NROWS + segs[i] * 256 + lane * 4);
        }
#pragma unroll
        for (int i = 0; i < 8; ++i) {
            const int row = rows[i];
            const int c0 = segs[i] * 256 + lane * 4;
            unsigned nib = (unsigned)(av[i].x > 0 || c0 == row)
                         | ((unsigned)(av[i].y > 0 || c0 + 1 == row) << 1)
                         | ((unsigned)(av[i].z > 0 || c0 + 2 == row) << 2)
                         | ((unsigned)(av[i].w > 0 || c0 + 3 == row) << 3);
            unsigned v = nib << ((lane & 7) * 4);
            v |= __shfl_xor((int)v, 1, 64);
            v |= __shfl_xor((int)v, 2, 64);
            v |= __shfl_xor((int)v, 4, 64);
            if ((lane & 7) == 0)
                mask[row * 128 + segs[i] * 8 + (lane >> 3)] = v;
        }
    } else {
        // ---- pack Wo/W1/W2 (327680 floats) ----
        int i = (b - 2816) * 2048 + tid * 8;
        const float* src; int off;
        if (i < 65536)       { src = Wo; off = i; }
        else if (i < 196608) { src = W1; off = i - 65536; }
        else                 { src = W2; off = i - 196608; }
        float4 a = *(const float4*)(src + off);
        float4 c = *(const float4*)(src + off + 4);
        *(s16x8*)(Wb + i) = pack8(a, c);
    }
}

// ---------------------------------------------------------------------------
// Dispatch 2: flash attention. rs-VALU row-sums + unroll 1 to shave VGPRs
// toward 64 (8 waves/SIMD -> whole 2048-block grid in one round). NO
// occupancy forcing (launch_bounds(256,8) miscompiled in round 9).
__global__ __launch_bounds__(256) void attn_kernel(const short* __restrict__ Qb,
                                                   const short* __restrict__ Kb,
                                                   const short* __restrict__ Vtb,
                                                   const unsigned* __restrict__ mask,
                                                   float* __restrict__ Opart,
                                                   float* __restrict__ lpart) {
    __shared__ union {
        short sP[2][16 * PSTRIDE];
        float sO[HDIM][OSTRIDE];
    } u[4];
    __shared__ float sl[4][32];

    const int tid = threadIdx.x;
    const int wv = tid >> 6, lane = tid & 63;
    const int quad = lane >> 4, col = lane & 15;
    const int khalf = blockIdx.x & 1;
    const int h = (blockIdx.x >> 1) & 7;
    const int q0 = (blockIdx.x >> 4) * 32;
    const int kw = khalf * 2048 + wv * 512;

    s16x8 qf[2];
    qf[0] = *(const s16x8*)(Qb + (size_t)(q0 + col) * DMODEL + h * HDIM + quad * 8);
    qf[1] = *(const s16x8*)(Qb + (size_t)(q0 + 16 + col) * DMODEL + h * HDIM + quad * 8);

    const short* kp  = Kb + (size_t)h * NROWS * HDIM + (size_t)(kw + col) * HDIM + quad * 8;
    const short* vp0 = Vtb + (size_t)(h * HDIM + col) * NROWS + kw + quad * 8;
    const short* vp1 = vp0 + (size_t)16 * NROWS;
    const unsigned* mp0 = mask + (size_t)(q0 + col) * 128 + (kw >> 5);
    const unsigned* mp1 = mp0 + 16 * 128;

    f32x4 zero = {0.f, 0.f, 0.f, 0.f};
    f32x4 acc[2][2] = {{zero, zero}, {zero, zero}};
    float rs[2] = {0.f, 0.f};
    const f32x4 cinit = {-M2C, -M2C, -M2C, -M2C};

#pragma unroll 1
    for (int it = 0; it < 8; ++it) {
        const short* k = kp + it * 64 * HDIM;
        s16x8 kf0 = *(const s16x8*)(k);
        s16x8 kf1 = *(const s16x8*)(k + 16 * HDIM);
        s16x8 kf2 = *(const s16x8*)(k + 32 * HDIM);
        s16x8 kf3 = *(const s16x8*)(k + 48 * HDIM);
        uint2 w0 = *(const uint2*)(mp0 + it * 2);
        uint2 w1 = *(const uint2*)(mp1 + it * 2);
        const short* v0 = vp0 + it * 64;
        const short* v1 = vp1 + it * 64;
        s16x8 vf00 = *(const s16x8*)(v0);
        s16x8 vf01 = *(const s16x8*)(v0 + 32);
        s16x8 vf10 = *(const s16x8*)(v1);
        s16x8 vf11 = *(const s16x8*)(v1 + 32);

#pragma unroll
        for (int qs = 0; qs < 2; ++qs) {
            unsigned wlo = (qs ? w1.x : w0.x) >> (quad * 4);
            unsigned whi = (qs ? w1.y : w0.y) >> (quad * 4);
            f32x4 st[4];
            st[0] = __builtin_amdgcn_mfma_f32_16x16x32_bf16(kf0, qf[qs], cinit, 0, 0, 0);
            st[1] = __builtin_amdgcn_mfma_f32_16x16x32_bf16(kf1, qf[qs], cinit, 0, 0, 0);
            st[2] = __builtin_amdgcn_mfma_f32_16x16x32_bf16(kf2, qf[qs], cinit, 0, 0, 0);
            st[3] = __builtin_amdgcn_mfma_f32_16x16x32_bf16(kf3, qf[qs], cinit, 0, 0, 0);

            float p[4][4];
            float r0 = 0.f;
#pragma unroll
            for (int t = 0; t < 4; ++t) {
                unsigned wm = (t < 2) ? wlo : whi;
#pragma unroll
                for (int r = 0; r < 4; ++r) {
                    float e = fexp2(st[t][r]);
                    bool ok = (wm & (1u << ((t & 1) * 16 + r))) != 0u;
                    p[t][r] = ok ? e : 0.f;
                    r0 += p[t][r];
                }
            }
            rs[qs] += r0;

            short* pb = &u[wv].sP[qs][0];
#pragma unroll
            for (int t = 0; t < 4; ++t) {
                uint2 pr;
                pr.x = pk_bf16(p[t][0], p[t][1]);
                pr.y = pk_bf16(p[t][2], p[t][3]);
                *(uint2*)(pb + col * PSTRIDE + t * 16 + quad * 4) = pr;
            }
            s16x8 pb0 = *(const s16x8*)(pb + col * PSTRIDE + quad * 8);
            s16x8 pb1 = *(const s16x8*)(pb + col * PSTRIDE + 32 + quad * 8);

            acc[qs][0] = __builtin_amdgcn_mfma_f32_16x16x32_bf16(vf00, pb0, acc[qs][0], 0, 0, 0);
            acc[qs][0] = __builtin_amdgcn_mfma_f32_16x16x32_bf16(vf01, pb1, acc[qs][0], 0, 0, 0);
            acc[qs][1] = __builtin_amdgcn_mfma_f32_16x16x32_bf16(vf10, pb0, acc[qs][1], 0, 0, 0);
            acc[qs][1] = __builtin_amdgcn_mfma_f32_16x16x32_bf16(vf11, pb1, acc[qs][1], 0, 0, 0);
        }
    }

#pragma unroll
    for (int qs = 0; qs < 2; ++qs) {
        float r = rs[qs];
        r += __shfl_xor(r, 16, 64);
        r += __shfl_xor(r, 32, 64);
        if (lane < 16) sl[wv][qs * 16 + col] = r;
#pragma unroll
        for (int rr = 0; rr < 4; ++rr) {
            u[wv].sO[quad * 4 + rr][qs * 16 + col]      = acc[qs][0][rr];
            u[wv].sO[16 + quad * 4 + rr][qs * 16 + col] = acc[qs][1][rr];
        }
    }
    __syncthreads();

    const int q = tid >> 3, hd0 = (tid & 7) * 4;
    float l = sl[0][q] + sl[1][q] + sl[2][q] + sl[3][q];
    float4 ov;
    ov.x = u[0].sO[hd0][q]     + u[1].sO[hd0][q]     + u[2].sO[hd0][q]     + u[3].sO[hd0][q];
    ov.y = u[0].sO[hd0 + 1][q] + u[1].sO[hd0 + 1][q] + u[2].sO[hd0 + 1][q] + u[3].sO[hd0 + 1][q];
    ov.z = u[0].sO[hd0 + 2][q] + u[1].sO[hd0 + 2][q] + u[2].sO[hd0 + 2][q] + u[3].sO[hd0 + 2][q];
    ov.w = u[0].sO[hd0 + 3][q] + u[1].sO[hd0 + 3][q] + u[2].sO[hd0 + 3][q] + u[3].sO[hd0 + 3][q];
    *(float4*)(Opart + (size_t)khalf * NM + (size_t)(q0 + q) * DMODEL + h * HDIM + hd0) = ov;
    if ((tid & 7) == 0) lpart[khalf * NROWS * NHEAD + (q0 + q) * NHEAD + h] = l;
}

// ---------------------------------------------------------------------------
// Dispatch 3: post-attention chain per 16-row stripe (round-8 proven).
__global__ __launch_bounds__(256) void mega_kernel(
        const float* __restrict__ Opart, const float* __restrict__ lpart,
        const float* __restrict__ X,
        const short* __restrict__ Wob, const short* __restrict__ W1b,
        const short* __restrict__ W2b,
        const float* __restrict__ bo,
        const float* __restrict__ g1, const float* __restrict__ be1,
        const float* __restrict__ b1, const float* __restrict__ b2,
        const float* __restrict__ g2, const float* __restrict__ be2,
        float* __restrict__ out) {
    __shared__ union { short sA[16 * SA_S]; short sR[16 * SR_S]; } uu;
    __shared__ float sH[16 * SH_S];
    __shared__ short sY[16 * SY_S];

    const int tid = threadIdx.x;
    const int wv = tid >> 6, lane = tid & 63;
    const int quad = lane >> 4, col = lane & 15;
    const int n0 = blockIdx.x * 16;
    const int rr_ = tid >> 4, cg = tid & 15;
    const int n_ln = n0 + rr_;
    f32x4 zero = {0.f, 0.f, 0.f, 0.f};

    // ---- Stage A: normalized merged O -> sA (bf16) ----
    {
        const int head = cg >> 1;
        float li = 1.f / (lpart[(size_t)n_ln * NHEAD + head] +
                          lpart[(size_t)NROWS * NHEAD + (size_t)n_ln * NHEAD + head]);
        const float* p0 = Opart + (size_t)n_ln * DMODEL + cg * 16;
        const float* p1 = p0 + NM;
        short* dst = &uu.sA[rr_ * SA_S + cg * 16];
#pragma unroll
        for (int j = 0; j < 4; ++j) {
            float4 a = ((const float4*)p0)[j];
            float4 b = ((const float4*)p1)[j];
            uint2 w;
            w.x = pk_bf16((a.x + b.x) * li, (a.y + b.y) * li);
            w.y = pk_bf16((a.z + b.z) * li, (a.w + b.w) * li);
            *(uint2*)(dst + j * 4) = w;
        }
    }
    __syncthreads();

    // ---- Stage A2: h = Anorm · Wo^T + bo ----
    {
        const int o0 = wv * 64;
        f32x4 acc[4] = {zero, zero, zero, zero};
#pragma unroll
        for (int k0 = 0; k0 < DMODEL; k0 += 32) {
            s16x8 af = *(const s16x8*)&uu.sA[col * SA_S + k0 + quad * 8];
#pragma unroll
            for (int t = 0; t < 4; ++t) {
                s16x8 bf = *(const s16x8*)(Wob + (size_t)(o0 + t * 16 + col) * DMODEL + k0 + quad * 8);
                acc[t] = __builtin_amdgcn_mfma_f32_16x16x32_bf16(af, bf, acc[t], 0, 0, 0);
            }
        }
#pragma unroll
        for (int t = 0; t < 4; ++t) {
            int o = o0 + t * 16 + col;
            float bv = bo[o];
#pragma unroll
            for (int r = 0; r < 4; ++r)
                sH[(quad * 4 + r) * SH_S + o] = acc[t][r] + bv;
        }
    }
    __syncthreads();

    // ---- LN1 ----
    float y1v[16];
    {
        const float* xp = X + (size_t)n_ln * DMODEL + cg * 16;
        float v[16];
        float s = 0.f;
#pragma unroll
        for (int j = 0; j < 4; ++j) {
            float4 xv = ((const float4*)xp)[j];
            float4 hv = *(const float4*)&sH[rr_ * SH_S + cg * 16 + j * 4];
            v[j * 4 + 0] = xv.x + hv.x; v[j * 4 + 1] = xv.y + hv.y;
            v[j * 4 + 2] = xv.z + hv.z; v[j * 4 + 3] = xv.w + hv.w;
            s += v[j * 4] + v[j * 4 + 1] + v[j * 4 + 2] + v[j * 4 + 3];
        }
#pragma unroll
        for (int m = 1; m < 16; m <<= 1) s += __shfl_xor(s, m, 64);
        float mean = s * (1.f / 256.f);
        float q = 0.f;
#pragma unroll
        for (int i = 0; i < 16; ++i) { v[i] -= mean; q += v[i] * v[i]; }
#pragma unroll
        for (int m = 1; m < 16; m <<= 1) q += __shfl_xor(q, m, 64);
        float rstd = rsqrtf(q * (1.f / 256.f) + 1e-5f);
        const float* gp = g1 + cg * 16;
        const float* bp = be1 + cg * 16;
        short* dst = &sY[rr_ * SY_S + cg * 16];
#pragma unroll
        for (int j = 0; j < 4; ++j) {
            float4 gv = ((const float4*)gp)[j];
            float4 bev = ((const float4*)bp)[j];
            float a0 = v[j * 4 + 0] * rstd * gv.x + bev.x;
            float a1 = v[j * 4 + 1] * rstd * gv.y + bev.y;
            float a2 = v[j * 4 + 2] * rstd * gv.z + bev.z;
            float a3 = v[j * 4 + 3] * rstd * gv.w + bev.w;
            y1v[j * 4 + 0] = a0; y1v[j * 4 + 1] = a1;
            y1v[j * 4 + 2] = a2; y1v[j * 4 + 3] = a3;
            uint2 w;
            w.x = pk_bf16(a0, a1);
            w.y = pk_bf16(a2, a3);
            *(uint2*)(dst + j * 4) = w;
        }
    }
    __syncthreads();

    // ---- Stage B: relu(y1 · W1^T + b1) -> sR ----
    {
        const int o0 = wv * 128;
        f32x4 acc[8] = {zero, zero, zero, zero, zero, zero, zero, zero};
#pragma unroll
        for (int k0 = 0; k0 < DMODEL; k0 += 32) {
            s16x8 af = *(const s16x8*)&sY[col * SY_S + k0 + quad * 8];
#pragma unroll
            for (int t = 0; t < 8; ++t) {
                s16x8 bf = *(const s16x8*)(W1b + (size_t)(o0 + t * 16 + col) * DMODEL + k0 + quad * 8);
                acc[t] = __builtin_amdgcn_mfma_f32_16x16x32_bf16(af, bf, acc[t], 0, 0, 0);
            }
        }
#pragma unroll
        for (int t = 0; t < 8; ++t) {
            int o = o0 + t * 16 + col;
            float bv = b1[o];
#pragma unroll
            for (int r = 0; r < 4; ++r)
                uu.sR[(quad * 4 + r) * SR_S + o] = bf16r(fmaxf(acc[t][r] + bv, 0.f));
        }
    }
    __syncthreads();

    // ---- Stage C: t2 = r · W2^T + b2 -> sH ----
    {
        const int o0 = wv * 64;
        f32x4 acc[4] = {zero, zero, zero, zero};
#pragma unroll
        for (int k0 = 0; k0 < 512; k0 += 32) {
            s16x8 af = *(const s16x8*)&uu.sR[col * SR_S + k0 + quad * 8];
#pragma unroll
            for (int t = 0; t < 4; ++t) {
                s16x8 bf = *(const s16x8*)(W2b + (size_t)(o0 + t * 16 + col) * 512 + k0 + quad * 8);
                acc[t] = __builtin_amdgcn_mfma_f32_16x16x32_bf16(af, bf, acc[t], 0, 0, 0);
            }
        }
#pragma unroll
        for (int t = 0; t < 4; ++t) {
            int o = o0 + t * 16 + col;
            float bv = b2[o];
#pragma unroll
            for (int r = 0; r < 4; ++r)
                sH[(quad * 4 + r) * SH_S + o] = acc[t][r] + bv;
        }
    }
    __syncthreads();

    // ---- LN2 ----
    {
        float v[16];
        float s = 0.f;
#pragma unroll
        for (int j = 0; j < 4; ++j) {
            float4 hv = *(const float4*)&sH[rr_ * SH_S + cg * 16 + j * 4];
            v[j * 4 + 0] = y1v[j * 4 + 0] + hv.x; v[j * 4 + 1] = y1v[j * 4 + 1] + hv.y;
            v[j * 4 + 2] = y1v[j * 4 + 2] + hv.z; v[j * 4 + 3] = y1v[j * 4 + 3] + hv.w;
            s += v[j * 4] + v[j * 4 + 1] + v[j * 4 + 2] + v[j * 4 + 3];
        }
#pragma unroll
        for (int m = 1; m < 16; m <<= 1) s += __shfl_xor(s, m, 64);
        float mean = s * (1.f / 256.f);
        float q = 0.f;
#pragma unroll
        for (int i = 0; i < 16; ++i) { v[i] -= mean; q += v[i] * v[i]; }
#pragma unroll
        for (int m = 1; m < 16; m <<= 1) q += __shfl_xor(q, m, 64);
        float rstd = rsqrtf(q * (1.f / 256.f) + 1e-5f);
        const float* gp = g2 + cg * 16;
        const float* bp = be2 + cg * 16;
        float* op = out + (size_t)n_ln * DMODEL + cg * 16;
#pragma unroll
        for (int j = 0; j < 4; ++j) {
            float4 gv = ((const float4*)gp)[j];
            float4 bev = ((const float4*)bp)[j];
            float4 y;
            y.x = v[j * 4 + 0] * rstd * gv.x + bev.x;
            y.y = v[j * 4 + 1] * rstd * gv.y + bev.y;
            y.z = v[j * 4 + 2] * rstd * gv.z + bev.z;
            y.w = v[j * 4 + 3] * rstd * gv.w + bev.w;
            ((float4*)op)[j] = y;
        }
    }
}

// ---------------------------------------------------------------------------
extern "C" void kernel_launch(void* const* d_in, const int* in_sizes, int n_in,
                              void* d_out, int out_size, void* d_ws, size_t ws_size,
                              hipStream_t stream) {
    const float* x   = (const float*)d_in[0];
    const int*   adj = (const int*)d_in[1];
    const float* Wq  = (const float*)d_in[2];
    const float* Wk  = (const float*)d_in[3];
    const float* Wv  = (const float*)d_in[4];
    const float* bq  = (const float*)d_in[5];
    const float* bk  = (const float*)d_in[6];
    const float* bv  = (const float*)d_in[7];
    const float* Wo  = (const float*)d_in[8];
    const float* bo  = (const float*)d_in[9];
    const float* g1  = (const float*)d_in[10];
    const float* be1 = (const float*)d_in[11];
    const float* W1  = (const float*)d_in[12];
    const float* b1  = (const float*)d_in[13];
    const float* W2  = (const float*)d_in[14];
    const float* b2  = (const float*)d_in[15];
    const float* g2  = (const float*)d_in[16];
    const float* be2 = (const float*)d_in[17];
    float* out = (float*)d_out;

    char* p = (char*)d_ws;
    unsigned* mask = (unsigned*)p; p += (size_t)NROWS * 128 * 4;          //  2 MB
    short* Wb    = (short*)p;      p += (size_t)327680 * 2;               // .64 MB
    short* Qb    = (short*)p;      p += (size_t)NM * 2;                   //  2 MB
    short* Kb    = (short*)p;      p += (size_t)NM * 2;                   //  2 MB
    short* Vtb   = (short*)p;      p += (size_t)NM * 2;                   //  2 MB
    float* Opart = (float*)p;      p += (size_t)2 * NM * 4;               //  8 MB
    float* lpart = (float*)p;      p += (size_t)2 * NROWS * NHEAD * 4;    // .25 MB

    qkvprep_kernel<<<dim3(2976), dim3(256), 0, stream>>>(
        x, Wq, Wk, Wv, bq, bk, bv, adj, mask, Wo, W1, W2, Wb, Qb, Kb, Vtb);
    attn_kernel<<<dim3(2048), dim3(256), 0, stream>>>(Qb, Kb, Vtb, mask, Opart, lpart);
    mega_kernel<<<dim3(256), dim3(256), 0, stream>>>(
        Opart, lpart, x, Wb, Wb + 65536, Wb + 196608,
        bo, g1, be1, b1, b2, g2, be2, out);
}

// Round 11
// 233.442 us; speedup vs baseline: 1.2375x; 1.0173x over previous
//
#include <hip/hip_runtime.h>
#include <hip/hip_bf16.h>

typedef __attribute__((ext_vector_type(4))) float f32x4;
typedef __attribute__((ext_vector_type(8))) short s16x8;

#define NROWS 4096
#define DMODEL 256
#define NHEAD 8
#define HDIM 32
#define PSTRIDE 72     // attn P-scratch row: 144 B, 16B-aligned
#define OSTRIDE 33     // attn sO row
#define M2C 24.0f      // fixed softmax max (log2 domain)
#define NM (NROWS * DMODEL)
// mega-kernel LDS strides
#define SA_S 264
#define SH_S 268
#define SY_S 264
#define SR_S 520

__device__ __forceinline__ short bf16r(float f) {
    union { float f; unsigned u; } v; v.f = f;
    unsigned r = v.u + 0x7fffu + ((v.u >> 16) & 1u);  // RNE
    return (short)(r >> 16);
}

__device__ __forceinline__ float fexp2(float x) {
    float r;
    asm("v_exp_f32 %0, %1" : "=v"(r) : "v"(x));
    return r;
}

__device__ __forceinline__ unsigned pk_bf16(float a, float b) {
#if __has_builtin(__builtin_amdgcn_cvt_pk_bf16_f32)
    typedef __bf16 bf2 __attribute__((ext_vector_type(2)));
    union { bf2 h; unsigned u; } c;
    c.h = __builtin_amdgcn_cvt_pk_bf16_f32(a, b);
    return c.u;
#else
    return (unsigned)(unsigned short)bf16r(a) | ((unsigned)(unsigned short)bf16r(b) << 16);
#endif
}

__device__ __forceinline__ s16x8 pack8(float4 a, float4 b) {
    s16x8 r;
    r[0] = bf16r(a.x); r[1] = bf16r(a.y); r[2] = bf16r(a.z); r[3] = bf16r(a.w);
    r[4] = bf16r(b.x); r[5] = bf16r(b.y); r[6] = bf16r(b.z); r[7] = bf16r(b.w);
    return r;
}

// ---------------------------------------------------------------------------
// Dispatch 1 (fused): blocks [0,768): QKV GEMM (f32 weights, inline pack);
// V output staged through LDS and stored COALESCED (old path was a 2-byte
// 64-cacheline scatter per wave-store). [768,2816): adj -> bitmask via int4
// loads + nibble/shuffle pack. [2816,2976): pack Wo/W1/W2 to bf16 into Wb.
__global__ __launch_bounds__(256) void qkvprep_kernel(
        const float* __restrict__ X,
        const float* __restrict__ Wq, const float* __restrict__ Wk,
        const float* __restrict__ Wv,
        const float* __restrict__ bq, const float* __restrict__ bk,
        const float* __restrict__ bv,
        const int* __restrict__ adj, unsigned* __restrict__ mask,
        const float* __restrict__ Wo, const float* __restrict__ W1,
        const float* __restrict__ W2, short* __restrict__ Wb,
        short* __restrict__ Qb, short* __restrict__ Kb,
        short* __restrict__ Vtb) {
    __shared__ short sT[64 * 72];   // V-tile transpose staging (9216 B)
    const int b = blockIdx.x;
    const int tid = threadIdx.x;
    const int lane = tid & 63;
    if (b < 768) {
        // ---- QKV GEMM: wave = 16 rows x 64 cols, 4 acc chains ----
        const int wv = tid >> 6;
        const int quad = lane >> 4, col = lane & 15;
        const int bx = b & 63, by = b >> 6;           // by 0..11
        const int o0 = by * 64;                        // 0..704
        const int z = o0 >> 8;
        const float* Wsrc = (z == 0) ? Wq : (z == 1 ? Wk : Wv);
        const float* bias = (z == 0) ? bq : (z == 1 ? bk : bv);
        const int ow0 = o0 & 255;
        const int n0 = bx * 64 + wv * 16;
        const float QSC = 0.25505653437397888f;        // log2e / sqrt(32)

        f32x4 zero = {0.f, 0.f, 0.f, 0.f};
        f32x4 acc[4] = {zero, zero, zero, zero};
        const float* ap = X + (size_t)(n0 + col) * DMODEL + quad * 8;
#pragma unroll
        for (int k0 = 0; k0 < DMODEL; k0 += 32) {
            float4 a0 = *(const float4*)(ap + k0);
            float4 a1 = *(const float4*)(ap + k0 + 4);
            s16x8 af = pack8(a0, a1);
#pragma unroll
            for (int t = 0; t < 4; ++t) {
                const float* wp = Wsrc + (size_t)(ow0 + t * 16 + col) * DMODEL + quad * 8 + k0;
                s16x8 bf = pack8(*(const float4*)wp, *(const float4*)(wp + 4));
                acc[t] = __builtin_amdgcn_mfma_f32_16x16x32_bf16(af, bf, acc[t], 0, 0, 0);
            }
        }
        if (z != 2) {
#pragma unroll
            for (int t = 0; t < 4; ++t) {
                const int oo = ow0 + t * 16 + col;
                float bvv = bias[oo];
#pragma unroll
                for (int r = 0; r < 4; ++r) {
                    int n = n0 + quad * 4 + r;
                    float v = acc[t][r] + bvv;
                    if (z == 0) Qb[(size_t)n * DMODEL + oo] = bf16r(v * QSC);
                    else        Kb[(size_t)(oo >> 5) * NROWS * HDIM + (size_t)n * HDIM + (oo & 31)] = bf16r(v);
                }
            }
        } else {
            // V: stage tile [oo 0..63][n 0..63] in LDS, store coalesced.
#pragma unroll
            for (int t = 0; t < 4; ++t) {
                const int oot = t * 16 + col;
                float bvv = bias[ow0 + oot];
#pragma unroll
                for (int r = 0; r < 4; ++r) {
                    int nn = wv * 16 + quad * 4 + r;
                    sT[oot * 72 + nn] = bf16r(acc[t][r] + bvv);
                }
            }
            __syncthreads();
            const int oor = tid >> 2, nseg = (tid & 3) * 16;
            s16x8 v0 = *(const s16x8*)&sT[oor * 72 + nseg];
            s16x8 v1 = *(const s16x8*)&sT[oor * 72 + nseg + 8];
            short* dst = Vtb + (size_t)(ow0 + oor) * NROWS + bx * 64 + nseg;
            *(s16x8*)dst = v0;         // wait: 16 shorts = two s16x8? no—
            // store 32 B total: two 16-B stores
            *(s16x8*)(dst + 8) = v1;
        }
    } else if (b < 2816) {
        // ---- adj -> bitmask: task = (row, 256-col segment); 65536 tasks ----
        const int waveid = (b - 768) * 4 + (tid >> 6);  // 0..8191
        int4 av[8];
        int rows[8], segs[8];
#pragma unroll
        for (int i = 0; i < 8; ++i) {
            const int task = waveid + i * 8192;          // 0..65535
            rows[i] = task >> 4; segs[i] = task & 15;
            av[i] = *(const int4*)(adj + (size_t)rows[i] * NROWS + segs[i] * 256 + lane * 4);
        }
#pragma unroll
        for (int i = 0; i < 8; ++i) {
            const int row = rows[i];
            const int c0 = segs[i] * 256 + lane * 4;
            unsigned nib = (unsigned)(av[i].x > 0 || c0 == row)
                         | ((unsigned)(av[i].y > 0 || c0 + 1 == row) << 1)
                         | ((unsigned)(av[i].z > 0 || c0 + 2 == row) << 2)
                         | ((unsigned)(av[i].w > 0 || c0 + 3 == row) << 3);
            unsigned v = nib << ((lane & 7) * 4);
            v |= __shfl_xor((int)v, 1, 64);
            v |= __shfl_xor((int)v, 2, 64);
            v |= __shfl_xor((int)v, 4, 64);
            if ((lane & 7) == 0)
                mask[row * 128 + segs[i] * 8 + (lane >> 3)] = v;
        }
    } else {
        // ---- pack Wo/W1/W2 (327680 floats) ----
        int i = (b - 2816) * 2048 + tid * 8;
        const float* src; int off;
        if (i < 65536)       { src = Wo; off = i; }
        else if (i < 196608) { src = W1; off = i - 65536; }
        else                 { src = W2; off = i - 196608; }
        float4 a = *(const float4*)(src + off);
        float4 c = *(const float4*)(src + off + 4);
        *(s16x8*)(Wb + i) = pack8(a, c);
    }
}

// ---------------------------------------------------------------------------
// Dispatch 2: flash attention — exact round-8 version (64.1 µs proven):
// ones-MFMA row-sums, unroll 2, no occupancy forcing.
__global__ __launch_bounds__(256) void attn_kernel(const short* __restrict__ Qb,
                                                   const short* __restrict__ Kb,
                                                   const short* __restrict__ Vtb,
                                                   const unsigned* __restrict__ mask,
                                                   float* __restrict__ Opart,
                                                   float* __restrict__ lpart) {
    __shared__ union {
        short sP[2][16 * PSTRIDE];
        float sO[HDIM][OSTRIDE];
    } u[4];
    __shared__ float sl[4][32];

    const int tid = threadIdx.x;
    const int wv = tid >> 6, lane = tid & 63;
    const int quad = lane >> 4, col = lane & 15;
    const int khalf = blockIdx.x & 1;
    const int h = (blockIdx.x >> 1) & 7;
    const int q0 = (blockIdx.x >> 4) * 32;
    const int kw = khalf * 2048 + wv * 512;

    s16x8 qf[2];
    qf[0] = *(const s16x8*)(Qb + (size_t)(q0 + col) * DMODEL + h * HDIM + quad * 8);
    qf[1] = *(const s16x8*)(Qb + (size_t)(q0 + 16 + col) * DMODEL + h * HDIM + quad * 8);

    const short* kp  = Kb + (size_t)h * NROWS * HDIM + (size_t)(kw + col) * HDIM + quad * 8;
    const short* vp0 = Vtb + (size_t)(h * HDIM + col) * NROWS + kw + quad * 8;
    const short* vp1 = vp0 + (size_t)16 * NROWS;
    const unsigned* mp0 = mask + (size_t)(q0 + col) * 128 + (kw >> 5);
    const unsigned* mp1 = mp0 + 16 * 128;

    const short onev = (col == 0) ? (short)0x3F80 : (short)0;
    const s16x8 ones = {onev, onev, onev, onev, onev, onev, onev, onev};

    f32x4 zero = {0.f, 0.f, 0.f, 0.f};
    f32x4 acc[2][2] = {{zero, zero}, {zero, zero}};
    f32x4 lacc[2] = {zero, zero};
    const f32x4 cinit = {-M2C, -M2C, -M2C, -M2C};

#pragma unroll 2
    for (int it = 0; it < 8; ++it) {
        const short* k = kp + it * 64 * HDIM;
        s16x8 kf0 = *(const s16x8*)(k);
        s16x8 kf1 = *(const s16x8*)(k + 16 * HDIM);
        s16x8 kf2 = *(const s16x8*)(k + 32 * HDIM);
        s16x8 kf3 = *(const s16x8*)(k + 48 * HDIM);
        uint2 w0 = *(const uint2*)(mp0 + it * 2);
        uint2 w1 = *(const uint2*)(mp1 + it * 2);
        const short* v0 = vp0 + it * 64;
        const short* v1 = vp1 + it * 64;
        s16x8 vf00 = *(const s16x8*)(v0);
        s16x8 vf01 = *(const s16x8*)(v0 + 32);
        s16x8 vf10 = *(const s16x8*)(v1);
        s16x8 vf11 = *(const s16x8*)(v1 + 32);

#pragma unroll
        for (int qs = 0; qs < 2; ++qs) {
            unsigned wlo = (qs ? w1.x : w0.x) >> (quad * 4);
            unsigned whi = (qs ? w1.y : w0.y) >> (quad * 4);
            f32x4 st[4];
            st[0] = __builtin_amdgcn_mfma_f32_16x16x32_bf16(kf0, qf[qs], cinit, 0, 0, 0);
            st[1] = __builtin_amdgcn_mfma_f32_16x16x32_bf16(kf1, qf[qs], cinit, 0, 0, 0);
            st[2] = __builtin_amdgcn_mfma_f32_16x16x32_bf16(kf2, qf[qs], cinit, 0, 0, 0);
            st[3] = __builtin_amdgcn_mfma_f32_16x16x32_bf16(kf3, qf[qs], cinit, 0, 0, 0);

            float p[4][4];
#pragma unroll
            for (int t = 0; t < 4; ++t) {
                unsigned wm = (t < 2) ? wlo : whi;
#pragma unroll
                for (int r = 0; r < 4; ++r) {
                    float e = fexp2(st[t][r]);
                    bool ok = (wm & (1u << ((t & 1) * 16 + r))) != 0u;
                    p[t][r] = ok ? e : 0.f;
                }
            }

            short* pb = &u[wv].sP[qs][0];
#pragma unroll
            for (int t = 0; t < 4; ++t) {
                uint2 pr;
                pr.x = pk_bf16(p[t][0], p[t][1]);
                pr.y = pk_bf16(p[t][2], p[t][3]);
                *(uint2*)(pb + col * PSTRIDE + t * 16 + quad * 4) = pr;
            }
            s16x8 pb0 = *(const s16x8*)(pb + col * PSTRIDE + quad * 8);
            s16x8 pb1 = *(const s16x8*)(pb + col * PSTRIDE + 32 + quad * 8);

            acc[qs][0] = __builtin_amdgcn_mfma_f32_16x16x32_bf16(vf00, pb0, acc[qs][0], 0, 0, 0);
            acc[qs][0] = __builtin_amdgcn_mfma_f32_16x16x32_bf16(vf01, pb1, acc[qs][0], 0, 0, 0);
            acc[qs][1] = __builtin_amdgcn_mfma_f32_16x16x32_bf16(vf10, pb0, acc[qs][1], 0, 0, 0);
            acc[qs][1] = __builtin_amdgcn_mfma_f32_16x16x32_bf16(vf11, pb1, acc[qs][1], 0, 0, 0);
            lacc[qs] = __builtin_amdgcn_mfma_f32_16x16x32_bf16(ones, pb0, lacc[qs], 0, 0, 0);
            lacc[qs] = __builtin_amdgcn_mfma_f32_16x16x32_bf16(ones, pb1, lacc[qs], 0, 0, 0);
        }
    }

#pragma unroll
    for (int qs = 0; qs < 2; ++qs) {
        if (lane < 16) sl[wv][qs * 16 + col] = lacc[qs][0];
#pragma unroll
        for (int rr = 0; rr < 4; ++rr) {
            u[wv].sO[quad * 4 + rr][qs * 16 + col]      = acc[qs][0][rr];
            u[wv].sO[16 + quad * 4 + rr][qs * 16 + col] = acc[qs][1][rr];
        }
    }
    __syncthreads();

    const int q = tid >> 3, hd0 = (tid & 7) * 4;
    float l = sl[0][q] + sl[1][q] + sl[2][q] + sl[3][q];
    float4 ov;
    ov.x = u[0].sO[hd0][q]     + u[1].sO[hd0][q]     + u[2].sO[hd0][q]     + u[3].sO[hd0][q];
    ov.y = u[0].sO[hd0 + 1][q] + u[1].sO[hd0 + 1][q] + u[2].sO[hd0 + 1][q] + u[3].sO[hd0 + 1][q];
    ov.z = u[0].sO[hd0 + 2][q] + u[1].sO[hd0 + 2][q] + u[2].sO[hd0 + 2][q] + u[3].sO[hd0 + 2][q];
    ov.w = u[0].sO[hd0 + 3][q] + u[1].sO[hd0 + 3][q] + u[2].sO[hd0 + 3][q] + u[3].sO[hd0 + 3][q];
    *(float4*)(Opart + (size_t)khalf * NM + (size_t)(q0 + q) * DMODEL + h * HDIM + hd0) = ov;
    if ((tid & 7) == 0) lpart[khalf * NROWS * NHEAD + (q0 + q) * NHEAD + h] = l;
}

// ---------------------------------------------------------------------------
// Dispatch 3: post-attention chain per 16-row stripe (round-8 proven).
__global__ __launch_bounds__(256) void mega_kernel(
        const float* __restrict__ Opart, const float* __restrict__ lpart,
        const float* __restrict__ X,
        const short* __restrict__ Wob, const short* __restrict__ W1b,
        const short* __restrict__ W2b,
        const float* __restrict__ bo,
        const float* __restrict__ g1, const float* __restrict__ be1,
        const float* __restrict__ b1, const float* __restrict__ b2,
        const float* __restrict__ g2, const float* __restrict__ be2,
        float* __restrict__ out) {
    __shared__ union { short sA[16 * SA_S]; short sR[16 * SR_S]; } uu;
    __shared__ float sH[16 * SH_S];
    __shared__ short sY[16 * SY_S];

    const int tid = threadIdx.x;
    const int wv = tid >> 6, lane = tid & 63;
    const int quad = lane >> 4, col = lane & 15;
    const int n0 = blockIdx.x * 16;
    const int rr_ = tid >> 4, cg = tid & 15;
    const int n_ln = n0 + rr_;
    f32x4 zero = {0.f, 0.f, 0.f, 0.f};

    // ---- Stage A: normalized merged O -> sA (bf16) ----
    {
        const int head = cg >> 1;
        float li = 1.f / (lpart[(size_t)n_ln * NHEAD + head] +
                          lpart[(size_t)NROWS * NHEAD + (size_t)n_ln * NHEAD + head]);
        const float* p0 = Opart + (size_t)n_ln * DMODEL + cg * 16;
        const float* p1 = p0 + NM;
        short* dst = &uu.sA[rr_ * SA_S + cg * 16];
#pragma unroll
        for (int j = 0; j < 4; ++j) {
            float4 a = ((const float4*)p0)[j];
            float4 b = ((const float4*)p1)[j];
            uint2 w;
            w.x = pk_bf16((a.x + b.x) * li, (a.y + b.y) * li);
            w.y = pk_bf16((a.z + b.z) * li, (a.w + b.w) * li);
            *(uint2*)(dst + j * 4) = w;
        }
    }
    __syncthreads();

    // ---- Stage A2: h = Anorm · Wo^T + bo ----
    {
        const int o0 = wv * 64;
        f32x4 acc[4] = {zero, zero, zero, zero};
#pragma unroll
        for (int k0 = 0; k0 < DMODEL; k0 += 32) {
            s16x8 af = *(const s16x8*)&uu.sA[col * SA_S + k0 + quad * 8];
#pragma unroll
            for (int t = 0; t < 4; ++t) {
                s16x8 bf = *(const s16x8*)(Wob + (size_t)(o0 + t * 16 + col) * DMODEL + k0 + quad * 8);
                acc[t] = __builtin_amdgcn_mfma_f32_16x16x32_bf16(af, bf, acc[t], 0, 0, 0);
            }
        }
#pragma unroll
        for (int t = 0; t < 4; ++t) {
            int o = o0 + t * 16 + col;
            float bv = bo[o];
#pragma unroll
            for (int r = 0; r < 4; ++r)
                sH[(quad * 4 + r) * SH_S + o] = acc[t][r] + bv;
        }
    }
    __syncthreads();

    // ---- LN1 ----
    float y1v[16];
    {
        const float* xp = X + (size_t)n_ln * DMODEL + cg * 16;
        float v[16];
        float s = 0.f;
#pragma unroll
        for (int j = 0; j < 4; ++j) {
            float4 xv = ((const float4*)xp)[j];
            float4 hv = *(const float4*)&sH[rr_ * SH_S + cg * 16 + j * 4];
            v[j * 4 + 0] = xv.x + hv.x; v[j * 4 + 1] = xv.y + hv.y;
            v[j * 4 + 2] = xv.z + hv.z; v[j * 4 + 3] = xv.w + hv.w;
            s += v[j * 4] + v[j * 4 + 1] + v[j * 4 + 2] + v[j * 4 + 3];
        }
#pragma unroll
        for (int m = 1; m < 16; m <<= 1) s += __shfl_xor(s, m, 64);
        float mean = s * (1.f / 256.f);
        float q = 0.f;
#pragma unroll
        for (int i = 0; i < 16; ++i) { v[i] -= mean; q += v[i] * v[i]; }
#pragma unroll
        for (int m = 1; m < 16; m <<= 1) q += __shfl_xor(q, m, 64);
        float rstd = rsqrtf(q * (1.f / 256.f) + 1e-5f);
        const float* gp = g1 + cg * 16;
        const float* bp = be1 + cg * 16;
        short* dst = &sY[rr_ * SY_S + cg * 16];
#pragma unroll
        for (int j = 0; j < 4; ++j) {
            float4 gv = ((const float4*)gp)[j];
            float4 bev = ((const float4*)bp)[j];
            float a0 = v[j * 4 + 0] * rstd * gv.x + bev.x;
            float a1 = v[j * 4 + 1] * rstd * gv.y + bev.y;
            float a2 = v[j * 4 + 2] * rstd * gv.z + bev.z;
            float a3 = v[j * 4 + 3] * rstd * gv.w + bev.w;
            y1v[j * 4 + 0] = a0; y1v[j * 4 + 1] = a1;
            y1v[j * 4 + 2] = a2; y1v[j * 4 + 3] = a3;
            uint2 w;
            w.x = pk_bf16(a0, a1);
            w.y = pk_bf16(a2, a3);
            *(uint2*)(dst + j * 4) = w;
        }
    }
    __syncthreads();

    // ---- Stage B: relu(y1 · W1^T + b1) -> sR ----
    {
        const int o0 = wv * 128;
        f32x4 acc[8] = {zero, zero, zero, zero, zero, zero, zero, zero};
#pragma unroll
        for (int k0 = 0; k0 < DMODEL; k0 += 32) {
            s16x8 af = *(const s16x8*)&sY[col * SY_S + k0 + quad * 8];
#pragma unroll
            for (int t = 0; t < 8; ++t) {
                s16x8 bf = *(const s16x8*)(W1b + (size_t)(o0 + t * 16 + col) * DMODEL + k0 + quad * 8);
                acc[t] = __builtin_amdgcn_mfma_f32_16x16x32_bf16(af, bf, acc[t], 0, 0, 0);
            }
        }
#pragma unroll
        for (int t = 0; t < 8; ++t) {
            int o = o0 + t * 16 + col;
            float bv = b1[o];
#pragma unroll
            for (int r = 0; r < 4; ++r)
                uu.sR[(quad * 4 + r) * SR_S + o] = bf16r(fmaxf(acc[t][r] + bv, 0.f));
        }
    }
    __syncthreads();

    // ---- Stage C: t2 = r · W2^T + b2 -> sH ----
    {
        const int o0 = wv * 64;
        f32x4 acc[4] = {zero, zero, zero, zero};
#pragma unroll
        for (int k0 = 0; k0 < 512; k0 += 32) {
            s16x8 af = *(const s16x8*)&uu.sR[col * SR_S + k0 + quad * 8];
#pragma unroll
            for (int t = 0; t < 4; ++t) {
                s16x8 bf = *(const s16x8*)(W2b + (size_t)(o0 + t * 16 + col) * 512 + k0 + quad * 8);
                acc[t] = __builtin_amdgcn_mfma_f32_16x16x32_bf16(af, bf, acc[t], 0, 0, 0);
            }
        }
#pragma unroll
        for (int t = 0; t < 4; ++t) {
            int o = o0 + t * 16 + col;
            float bv = b2[o];
#pragma unroll
            for (int r = 0; r < 4; ++r)
                sH[(quad * 4 + r) * SH_S + o] = acc[t][r] + bv;
        }
    }
    __syncthreads();

    // ---- LN2 ----
    {
        float v[16];
        float s = 0.f;
#pragma unroll
        for (int j = 0; j < 4; ++j) {
            float4 hv = *(const float4*)&sH[rr_ * SH_S + cg * 16 + j * 4];
            v[j * 4 + 0] = y1v[j * 4 + 0] + hv.x; v[j * 4 + 1] = y1v[j * 4 + 1] + hv.y;
            v[j * 4 + 2] = y1v[j * 4 + 2] + hv.z; v[j * 4 + 3] = y1v[j * 4 + 3] + hv.w;
            s += v[j * 4] + v[j * 4 + 1] + v[j * 4 + 2] + v[j * 4 + 3];
        }
#pragma unroll
        for (int m = 1; m < 16; m <<= 1) s += __shfl_xor(s, m, 64);
        float mean = s * (1.f / 256.f);
        float q = 0.f;
#pragma unroll
        for (int i = 0; i < 16; ++i) { v[i] -= mean; q += v[i] * v[i]; }
#pragma unroll
        for (int m = 1; m < 16; m <<= 1) q += __shfl_xor(q, m, 64);
        float rstd = rsqrtf(q * (1.f / 256.f) + 1e-5f);
        const float* gp = g2 + cg * 16;
        const float* bp = be2 + cg * 16;
        float* op = out + (size_t)n_ln * DMODEL + cg * 16;
#pragma unroll
        for (int j = 0; j < 4; ++j) {
            float4 gv = ((const float4*)gp)[j];
            float4 bev = ((const float4*)bp)[j];
            float4 y;
            y.x = v[j * 4 + 0] * rstd * gv.x + bev.x;
            y.y = v[j * 4 + 1] * rstd * gv.y + bev.y;
            y.z = v[j * 4 + 2] * rstd * gv.z + bev.z;
            y.w = v[j * 4 + 3] * rstd * gv.w + bev.w;
            ((float4*)op)[j] = y;
        }
    }
}

// ---------------------------------------------------------------------------
extern "C" void kernel_launch(void* const* d_in, const int* in_sizes, int n_in,
                              void* d_out, int out_size, void* d_ws, size_t ws_size,
                              hipStream_t stream) {
    const float* x   = (const float*)d_in[0];
    const int*   adj = (const int*)d_in[1];
    const float* Wq  = (const float*)d_in[2];
    const float* Wk  = (const float*)d_in[3];
    const float* Wv  = (const float*)d_in[4];
    const float* bq  = (const float*)d_in[5];
    const float* bk  = (const float*)d_in[6];
    const float* bv  = (const float*)d_in[7];
    const float* Wo  = (const float*)d_in[8];
    const float* bo  = (const float*)d_in[9];
    const float* g1  = (const float*)d_in[10];
    const float* be1 = (const float*)d_in[11];
    const float* W1  = (const float*)d_in[12];
    const float* b1  = (const float*)d_in[13];
    const float* W2  = (const float*)d_in[14];
    const float* b2  = (const float*)d_in[15];
    const float* g2  = (const float*)d_in[16];
    const float* be2 = (const float*)d_in[17];
    float* out = (float*)d_out;

    char* p = (char*)d_ws;
    unsigned* mask = (unsigned*)p; p += (size_t)NROWS * 128 * 4;          //  2 MB
    short* Wb    = (short*)p;      p += (size_t)327680 * 2;               // .64 MB
    short* Qb    = (short*)p;      p += (size_t)NM * 2;                   //  2 MB
    short* Kb    = (short*)p;      p += (size_t)NM * 2;                   //  2 MB
    short* Vtb   = (short*)p;      p += (size_t)NM * 2;                   //  2 MB
    float* Opart = (float*)p;      p += (size_t)2 * NM * 4;               //  8 MB
    float* lpart = (float*)p;      p += (size_t)2 * NROWS * NHEAD * 4;    // .25 MB

    qkvprep_kernel<<<dim3(2976), dim3(256), 0, stream>>>(
        x, Wq, Wk, Wv, bq, bk, bv, adj, mask, Wo, W1, W2, Wb, Qb, Kb, Vtb);
    attn_kernel<<<dim3(2048), dim3(256), 0, stream>>>(Qb, Kb, Vtb, mask, Opart, lpart);
    mega_kernel<<<dim3(256), dim3(256), 0, stream>>>(
        Opart, lpart, x, Wb, Wb + 65536, Wb + 196608,
        bo, g1, be1, b1, b2, g2, be2, out);
}

// Round 12
// 232.376 us; speedup vs baseline: 1.2432x; 1.0046x over previous
//
#include <hip/hip_runtime.h>
#include <hip/hip_bf16.h>

typedef __attribute__((ext_vector_type(4))) float f32x4;
typedef __attribute__((ext_vector_type(8))) short s16x8;

#define NROWS 4096
#define DMODEL 256
#define NHEAD 8
#define HDIM 32
#define PSTRIDE 72     // attn P-scratch row: 144 B, 16B-aligned
#define OSTRIDE 33     // attn sO row
#define M2C 24.0f      // fixed softmax max (log2 domain)
#define NM (NROWS * DMODEL)
// mega-kernel LDS strides
#define SA_S 264
#define SH_S 268
#define SY_S 264
#define SR_S 520

__device__ __forceinline__ short bf16r(float f) {
    union { float f; unsigned u; } v; v.f = f;
    unsigned r = v.u + 0x7fffu + ((v.u >> 16) & 1u);  // RNE
    return (short)(r >> 16);
}

__device__ __forceinline__ float fexp2(float x) {
    float r;
    asm("v_exp_f32 %0, %1" : "=v"(r) : "v"(x));
    return r;
}

__device__ __forceinline__ unsigned pk_bf16(float a, float b) {
#if __has_builtin(__builtin_amdgcn_cvt_pk_bf16_f32)
    typedef __bf16 bf2 __attribute__((ext_vector_type(2)));
    union { bf2 h; unsigned u; } c;
    c.h = __builtin_amdgcn_cvt_pk_bf16_f32(a, b);
    return c.u;
#else
    return (unsigned)(unsigned short)bf16r(a) | ((unsigned)(unsigned short)bf16r(b) << 16);
#endif
}

__device__ __forceinline__ s16x8 pack8(float4 a, float4 b) {
    s16x8 r;
    r[0] = bf16r(a.x); r[1] = bf16r(a.y); r[2] = bf16r(a.z); r[3] = bf16r(a.w);
    r[4] = bf16r(b.x); r[5] = bf16r(b.y); r[6] = bf16r(b.z); r[7] = bf16r(b.w);
    return r;
}

// ---------------------------------------------------------------------------
// Dispatch 1 (fused): blocks [0,768): QKV GEMM (f32 weights, inline pack);
// V staged through LDS, stored coalesced. [768,2816): adj -> bitmask via
// int4 loads + nibble/shuffle pack. [2816,2976): pack Wo/W1/W2 to bf16.
__global__ __launch_bounds__(256) void qkvprep_kernel(
        const float* __restrict__ X,
        const float* __restrict__ Wq, const float* __restrict__ Wk,
        const float* __restrict__ Wv,
        const float* __restrict__ bq, const float* __restrict__ bk,
        const float* __restrict__ bv,
        const int* __restrict__ adj, unsigned* __restrict__ mask,
        const float* __restrict__ Wo, const float* __restrict__ W1,
        const float* __restrict__ W2, short* __restrict__ Wb,
        short* __restrict__ Qb, short* __restrict__ Kb,
        short* __restrict__ Vtb) {
    __shared__ short sT[64 * 72];   // V-tile transpose staging (9216 B)
    const int b = blockIdx.x;
    const int tid = threadIdx.x;
    const int lane = tid & 63;
    if (b < 768) {
        const int wv = tid >> 6;
        const int quad = lane >> 4, col = lane & 15;
        const int bx = b & 63, by = b >> 6;           // by 0..11
        const int o0 = by * 64;                        // 0..704
        const int z = o0 >> 8;
        const float* Wsrc = (z == 0) ? Wq : (z == 1 ? Wk : Wv);
        const float* bias = (z == 0) ? bq : (z == 1 ? bk : bv);
        const int ow0 = o0 & 255;
        const int n0 = bx * 64 + wv * 16;
        const float QSC = 0.25505653437397888f;        // log2e / sqrt(32)

        f32x4 zero = {0.f, 0.f, 0.f, 0.f};
        f32x4 acc[4] = {zero, zero, zero, zero};
        const float* ap = X + (size_t)(n0 + col) * DMODEL + quad * 8;
#pragma unroll
        for (int k0 = 0; k0 < DMODEL; k0 += 32) {
            float4 a0 = *(const float4*)(ap + k0);
            float4 a1 = *(const float4*)(ap + k0 + 4);
            s16x8 af = pack8(a0, a1);
#pragma unroll
            for (int t = 0; t < 4; ++t) {
                const float* wp = Wsrc + (size_t)(ow0 + t * 16 + col) * DMODEL + quad * 8 + k0;
                s16x8 bf = pack8(*(const float4*)wp, *(const float4*)(wp + 4));
                acc[t] = __builtin_amdgcn_mfma_f32_16x16x32_bf16(af, bf, acc[t], 0, 0, 0);
            }
        }
        if (z != 2) {
#pragma unroll
            for (int t = 0; t < 4; ++t) {
                const int oo = ow0 + t * 16 + col;
                float bvv = bias[oo];
#pragma unroll
                for (int r = 0; r < 4; ++r) {
                    int n = n0 + quad * 4 + r;
                    float v = acc[t][r] + bvv;
                    if (z == 0) Qb[(size_t)n * DMODEL + oo] = bf16r(v * QSC);
                    else        Kb[(size_t)(oo >> 5) * NROWS * HDIM + (size_t)n * HDIM + (oo & 31)] = bf16r(v);
                }
            }
        } else {
            // V: stage [oo 0..63][n 0..63] tile in LDS, store coalesced.
#pragma unroll
            for (int t = 0; t < 4; ++t) {
                const int oot = t * 16 + col;
                float bvv = bias[ow0 + oot];
#pragma unroll
                for (int r = 0; r < 4; ++r) {
                    int nn = wv * 16 + quad * 4 + r;
                    sT[oot * 72 + nn] = bf16r(acc[t][r] + bvv);
                }
            }
            __syncthreads();
            const int oor = tid >> 2, nseg = (tid & 3) * 16;
            s16x8 v0 = *(const s16x8*)&sT[oor * 72 + nseg];
            s16x8 v1 = *(const s16x8*)&sT[oor * 72 + nseg + 8];
            short* dst = Vtb + (size_t)(ow0 + oor) * NROWS + bx * 64 + nseg;
            *(s16x8*)dst = v0;
            *(s16x8*)(dst + 8) = v1;
        }
    } else if (b < 2816) {
        const int waveid = (b - 768) * 4 + (tid >> 6);  // 0..8191
        int4 av[8];
        int rows[8], segs[8];
#pragma unroll
        for (int i = 0; i < 8; ++i) {
            const int task = waveid + i * 8192;          // 0..65535
            rows[i] = task >> 4; segs[i] = task & 15;
            av[i] = *(const int4*)(adj + (size_t)rows[i] * NROWS + segs[i] * 256 + lane * 4);
        }
#pragma unroll
        for (int i = 0; i < 8; ++i) {
            const int row = rows[i];
            const int c0 = segs[i] * 256 + lane * 4;
            unsigned nib = (unsigned)(av[i].x > 0 || c0 == row)
                         | ((unsigned)(av[i].y > 0 || c0 + 1 == row) << 1)
                         | ((unsigned)(av[i].z > 0 || c0 + 2 == row) << 2)
                         | ((unsigned)(av[i].w > 0 || c0 + 3 == row) << 3);
            unsigned v = nib << ((lane & 7) * 4);
            v |= __shfl_xor((int)v, 1, 64);
            v |= __shfl_xor((int)v, 2, 64);
            v |= __shfl_xor((int)v, 4, 64);
            if ((lane & 7) == 0)
                mask[row * 128 + segs[i] * 8 + (lane >> 3)] = v;
        }
    } else {
        int i = (b - 2816) * 2048 + tid * 8;
        const float* src; int off;
        if (i < 65536)       { src = Wo; off = i; }
        else if (i < 196608) { src = W1; off = i - 65536; }
        else                 { src = W2; off = i - 196608; }
        float4 a = *(const float4*)(src + off);
        float4 c = *(const float4*)(src + off + 4);
        *(s16x8*)(Wb + i) = pack8(a, c);
    }
}

// ---------------------------------------------------------------------------
// Dispatch 2: flash attention. VGPR diet targeting <=64 (8 blocks/CU -> all
// 2048 blocks in one scheduling round): rs-VALU row-sums (drops ones+lacc,
// -12 regs), C=zero with -M2C folded into the exp argument (-4 regs),
// unroll 2 kept for load batching. No launch_bounds occupancy forcing.
__global__ __launch_bounds__(256) void attn_kernel(const short* __restrict__ Qb,
                                                   const short* __restrict__ Kb,
                                                   const short* __restrict__ Vtb,
                                                   const unsigned* __restrict__ mask,
                                                   float* __restrict__ Opart,
                                                   float* __restrict__ lpart) {
    __shared__ union {
        short sP[2][16 * PSTRIDE];
        float sO[HDIM][OSTRIDE];
    } u[4];
    __shared__ float sl[4][32];

    const int tid = threadIdx.x;
    const int wv = tid >> 6, lane = tid & 63;
    const int quad = lane >> 4, col = lane & 15;
    const int khalf = blockIdx.x & 1;
    const int h = (blockIdx.x >> 1) & 7;
    const int q0 = (blockIdx.x >> 4) * 32;
    const int kw = khalf * 2048 + wv * 512;

    s16x8 qf[2];
    qf[0] = *(const s16x8*)(Qb + (size_t)(q0 + col) * DMODEL + h * HDIM + quad * 8);
    qf[1] = *(const s16x8*)(Qb + (size_t)(q0 + 16 + col) * DMODEL + h * HDIM + quad * 8);

    const short* kp  = Kb + (size_t)h * NROWS * HDIM + (size_t)(kw + col) * HDIM + quad * 8;
    const short* vp0 = Vtb + (size_t)(h * HDIM + col) * NROWS + kw + quad * 8;
    const short* vp1 = vp0 + (size_t)16 * NROWS;
    const unsigned* mp0 = mask + (size_t)(q0 + col) * 128 + (kw >> 5);
    const unsigned* mp1 = mp0 + 16 * 128;

    f32x4 zero = {0.f, 0.f, 0.f, 0.f};
    f32x4 acc[2][2] = {{zero, zero}, {zero, zero}};
    float rs[2] = {0.f, 0.f};

#pragma unroll 2
    for (int it = 0; it < 8; ++it) {
        const short* k = kp + it * 64 * HDIM;
        s16x8 kf0 = *(const s16x8*)(k);
        s16x8 kf1 = *(const s16x8*)(k + 16 * HDIM);
        s16x8 kf2 = *(const s16x8*)(k + 32 * HDIM);
        s16x8 kf3 = *(const s16x8*)(k + 48 * HDIM);
        uint2 w0 = *(const uint2*)(mp0 + it * 2);
        uint2 w1 = *(const uint2*)(mp1 + it * 2);
        const short* v0 = vp0 + it * 64;
        const short* v1 = vp1 + it * 64;
        s16x8 vf00 = *(const s16x8*)(v0);
        s16x8 vf01 = *(const s16x8*)(v0 + 32);
        s16x8 vf10 = *(const s16x8*)(v1);
        s16x8 vf11 = *(const s16x8*)(v1 + 32);

#pragma unroll
        for (int qs = 0; qs < 2; ++qs) {
            unsigned wlo = (qs ? w1.x : w0.x) >> (quad * 4);
            unsigned whi = (qs ? w1.y : w0.y) >> (quad * 4);
            f32x4 st[4];
            st[0] = __builtin_amdgcn_mfma_f32_16x16x32_bf16(kf0, qf[qs], zero, 0, 0, 0);
            st[1] = __builtin_amdgcn_mfma_f32_16x16x32_bf16(kf1, qf[qs], zero, 0, 0, 0);
            st[2] = __builtin_amdgcn_mfma_f32_16x16x32_bf16(kf2, qf[qs], zero, 0, 0, 0);
            st[3] = __builtin_amdgcn_mfma_f32_16x16x32_bf16(kf3, qf[qs], zero, 0, 0, 0);

            float p[4][4];
            float r0 = 0.f;
#pragma unroll
            for (int t = 0; t < 4; ++t) {
                unsigned wm = (t < 2) ? wlo : whi;
#pragma unroll
                for (int r = 0; r < 4; ++r) {
                    float e = fexp2(st[t][r] - M2C);
                    bool ok = (wm & (1u << ((t & 1) * 16 + r))) != 0u;
                    p[t][r] = ok ? e : 0.f;
                    r0 += p[t][r];
                }
            }
            rs[qs] += r0;

            short* pb = &u[wv].sP[qs][0];
#pragma unroll
            for (int t = 0; t < 4; ++t) {
                uint2 pr;
                pr.x = pk_bf16(p[t][0], p[t][1]);
                pr.y = pk_bf16(p[t][2], p[t][3]);
                *(uint2*)(pb + col * PSTRIDE + t * 16 + quad * 4) = pr;
            }
            s16x8 pb0 = *(const s16x8*)(pb + col * PSTRIDE + quad * 8);
            s16x8 pb1 = *(const s16x8*)(pb + col * PSTRIDE + 32 + quad * 8);

            acc[qs][0] = __builtin_amdgcn_mfma_f32_16x16x32_bf16(vf00, pb0, acc[qs][0], 0, 0, 0);
            acc[qs][0] = __builtin_amdgcn_mfma_f32_16x16x32_bf16(vf01, pb1, acc[qs][0], 0, 0, 0);
            acc[qs][1] = __builtin_amdgcn_mfma_f32_16x16x32_bf16(vf10, pb0, acc[qs][1], 0, 0, 0);
            acc[qs][1] = __builtin_amdgcn_mfma_f32_16x16x32_bf16(vf11, pb1, acc[qs][1], 0, 0, 0);
        }
    }

#pragma unroll
    for (int qs = 0; qs < 2; ++qs) {
        float r = rs[qs];
        r += __shfl_xor(r, 16, 64);
        r += __shfl_xor(r, 32, 64);
        if (lane < 16) sl[wv][qs * 16 + col] = r;
#pragma unroll
        for (int rr = 0; rr < 4; ++rr) {
            u[wv].sO[quad * 4 + rr][qs * 16 + col]      = acc[qs][0][rr];
            u[wv].sO[16 + quad * 4 + rr][qs * 16 + col] = acc[qs][1][rr];
        }
    }
    __syncthreads();

    const int q = tid >> 3, hd0 = (tid & 7) * 4;
    float l = sl[0][q] + sl[1][q] + sl[2][q] + sl[3][q];
    float4 ov;
    ov.x = u[0].sO[hd0][q]     + u[1].sO[hd0][q]     + u[2].sO[hd0][q]     + u[3].sO[hd0][q];
    ov.y = u[0].sO[hd0 + 1][q] + u[1].sO[hd0 + 1][q] + u[2].sO[hd0 + 1][q] + u[3].sO[hd0 + 1][q];
    ov.z = u[0].sO[hd0 + 2][q] + u[1].sO[hd0 + 2][q] + u[2].sO[hd0 + 2][q] + u[3].sO[hd0 + 2][q];
    ov.w = u[0].sO[hd0 + 3][q] + u[1].sO[hd0 + 3][q] + u[2].sO[hd0 + 3][q] + u[3].sO[hd0 + 3][q];
    *(float4*)(Opart + (size_t)khalf * NM + (size_t)(q0 + q) * DMODEL + h * HDIM + hd0) = ov;
    if ((tid & 7) == 0) lpart[khalf * NROWS * NHEAD + (q0 + q) * NHEAD + h] = l;
}

// ---------------------------------------------------------------------------
// Dispatch 3: post-attention chain per 16-row stripe, now 512 threads/block
// (8 waves -> 2 waves/SIMD: doubles TLP, halves per-stage serial latency).
__global__ __launch_bounds__(512) void mega_kernel(
        const float* __restrict__ Opart, const float* __restrict__ lpart,
        const float* __restrict__ X,
        const short* __restrict__ Wob, const short* __restrict__ W1b,
        const short* __restrict__ W2b,
        const float* __restrict__ bo,
        const float* __restrict__ g1, const float* __restrict__ be1,
        const float* __restrict__ b1, const float* __restrict__ b2,
        const float* __restrict__ g2, const float* __restrict__ be2,
        float* __restrict__ out) {
    __shared__ union { short sA[16 * SA_S]; short sR[16 * SR_S]; } uu;
    __shared__ float sH[16 * SH_S];
    __shared__ short sY[16 * SY_S];

    const int tid = threadIdx.x;
    const int wv = tid >> 6, lane = tid & 63;
    const int quad = lane >> 4, col = lane & 15;
    const int n0 = blockIdx.x * 16;
    // LN/elementwise phase map: 32 threads per row, 8 elems per thread
    const int rr_ = tid >> 5, c8 = (tid & 31) * 8;
    const int n_ln = n0 + rr_;
    f32x4 zero = {0.f, 0.f, 0.f, 0.f};

    // ---- Stage A: normalized merged O -> sA (bf16) ----
    {
        const int head = c8 >> 5;
        float li = 1.f / (lpart[(size_t)n_ln * NHEAD + head] +
                          lpart[(size_t)NROWS * NHEAD + (size_t)n_ln * NHEAD + head]);
        const float* p0 = Opart + (size_t)n_ln * DMODEL + c8;
        const float* p1 = p0 + NM;
        float4 a0 = ((const float4*)p0)[0], a1 = ((const float4*)p0)[1];
        float4 b0 = ((const float4*)p1)[0], b1v = ((const float4*)p1)[1];
        s16x8 w;
        *((unsigned*)&w + 0) = pk_bf16((a0.x + b0.x) * li, (a0.y + b0.y) * li);
        *((unsigned*)&w + 1) = pk_bf16((a0.z + b0.z) * li, (a0.w + b0.w) * li);
        *((unsigned*)&w + 2) = pk_bf16((a1.x + b1v.x) * li, (a1.y + b1v.y) * li);
        *((unsigned*)&w + 3) = pk_bf16((a1.z + b1v.z) * li, (a1.w + b1v.w) * li);
        *(s16x8*)&uu.sA[rr_ * SA_S + c8] = w;
    }
    __syncthreads();

    // ---- Stage A2: h = Anorm · Wo^T + bo (wave: 16 x 32) ----
    {
        const int o0 = wv * 32;
        f32x4 acc[2] = {zero, zero};
#pragma unroll
        for (int k0 = 0; k0 < DMODEL; k0 += 32) {
            s16x8 af = *(const s16x8*)&uu.sA[col * SA_S + k0 + quad * 8];
#pragma unroll
            for (int t = 0; t < 2; ++t) {
                s16x8 bf = *(const s16x8*)(Wob + (size_t)(o0 + t * 16 + col) * DMODEL + k0 + quad * 8);
                acc[t] = __builtin_amdgcn_mfma_f32_16x16x32_bf16(af, bf, acc[t], 0, 0, 0);
            }
        }
#pragma unroll
        for (int t = 0; t < 2; ++t) {
            int o = o0 + t * 16 + col;
            float bv = bo[o];
#pragma unroll
            for (int r = 0; r < 4; ++r)
                sH[(quad * 4 + r) * SH_S + o] = acc[t][r] + bv;
        }
    }
    __syncthreads();

    // ---- LN1: y1 = LN(x + h); 8 f32/thread in regs, bf16 -> sY ----
    float y1v[8];
    {
        const float* xp = X + (size_t)n_ln * DMODEL + c8;
        float v[8];
        float s = 0.f;
#pragma unroll
        for (int j = 0; j < 2; ++j) {
            float4 xv = ((const float4*)xp)[j];
            float4 hv = *(const float4*)&sH[rr_ * SH_S + c8 + j * 4];
            v[j * 4 + 0] = xv.x + hv.x; v[j * 4 + 1] = xv.y + hv.y;
            v[j * 4 + 2] = xv.z + hv.z; v[j * 4 + 3] = xv.w + hv.w;
            s += v[j * 4] + v[j * 4 + 1] + v[j * 4 + 2] + v[j * 4 + 3];
        }
#pragma unroll
        for (int m = 1; m < 32; m <<= 1) s += __shfl_xor(s, m, 64);
        float mean = s * (1.f / 256.f);
        float q = 0.f;
#pragma unroll
        for (int i = 0; i < 8; ++i) { v[i] -= mean; q += v[i] * v[i]; }
#pragma unroll
        for (int m = 1; m < 32; m <<= 1) q += __shfl_xor(q, m, 64);
        float rstd = rsqrtf(q * (1.f / 256.f) + 1e-5f);
        const float* gp = g1 + c8;
        const float* bp = be1 + c8;
        s16x8 w;
#pragma unroll
        for (int j = 0; j < 2; ++j) {
            float4 gv = ((const float4*)gp)[j];
            float4 bev = ((const float4*)bp)[j];
            float a0 = v[j * 4 + 0] * rstd * gv.x + bev.x;
            float a1 = v[j * 4 + 1] * rstd * gv.y + bev.y;
            float a2 = v[j * 4 + 2] * rstd * gv.z + bev.z;
            float a3 = v[j * 4 + 3] * rstd * gv.w + bev.w;
            y1v[j * 4 + 0] = a0; y1v[j * 4 + 1] = a1;
            y1v[j * 4 + 2] = a2; y1v[j * 4 + 3] = a3;
            *((unsigned*)&w + j * 2 + 0) = pk_bf16(a0, a1);
            *((unsigned*)&w + j * 2 + 1) = pk_bf16(a2, a3);
        }
        *(s16x8*)&sY[rr_ * SY_S + c8] = w;
    }
    __syncthreads();

    // ---- Stage B: relu(y1 · W1^T + b1) -> sR (wave: 16 x 64) ----
    {
        const int o0 = wv * 64;
        f32x4 acc[4] = {zero, zero, zero, zero};
#pragma unroll
        for (int k0 = 0; k0 < DMODEL; k0 += 32) {
            s16x8 af = *(const s16x8*)&sY[col * SY_S + k0 + quad * 8];
#pragma unroll
            for (int t = 0; t < 4; ++t) {
                s16x8 bf = *(const s16x8*)(W1b + (size_t)(o0 + t * 16 + col) * DMODEL + k0 + quad * 8);
                acc[t] = __builtin_amdgcn_mfma_f32_16x16x32_bf16(af, bf, acc[t], 0, 0, 0);
            }
        }
#pragma unroll
        for (int t = 0; t < 4; ++t) {
            int o = o0 + t * 16 + col;
            float bv = b1[o];
#pragma unroll
            for (int r = 0; r < 4; ++r)
                uu.sR[(quad * 4 + r) * SR_S + o] = bf16r(fmaxf(acc[t][r] + bv, 0.f));
        }
    }
    __syncthreads();

    // ---- Stage C: t2 = r · W2^T + b2 (wave: 16 x 32, K=512) -> sH ----
    {
        const int o0 = wv * 32;
        f32x4 acc[2] = {zero, zero};
#pragma unroll
        for (int k0 = 0; k0 < 512; k0 += 32) {
            s16x8 af = *(const s16x8*)&uu.sR[col * SR_S + k0 + quad * 8];
#pragma unroll
            for (int t = 0; t < 2; ++t) {
                s16x8 bf = *(const s16x8*)(W2b + (size_t)(o0 + t * 16 + col) * 512 + k0 + quad * 8);
                acc[t] = __builtin_amdgcn_mfma_f32_16x16x32_bf16(af, bf, acc[t], 0, 0, 0);
            }
        }
#pragma unroll
        for (int t = 0; t < 2; ++t) {
            int o = o0 + t * 16 + col;
            float bv = b2[o];
#pragma unroll
            for (int r = 0; r < 4; ++r)
                sH[(quad * 4 + r) * SH_S + o] = acc[t][r] + bv;
        }
    }
    __syncthreads();

    // ---- LN2: out = LN(y1 + t2) ----
    {
        float v[8];
        float s = 0.f;
#pragma unroll
        for (int j = 0; j < 2; ++j) {
            float4 hv = *(const float4*)&sH[rr_ * SH_S + c8 + j * 4];
            v[j * 4 + 0] = y1v[j * 4 + 0] + hv.x; v[j * 4 + 1] = y1v[j * 4 + 1] + hv.y;
            v[j * 4 + 2] = y1v[j * 4 + 2] + hv.z; v[j * 4 + 3] = y1v[j * 4 + 3] + hv.w;
            s += v[j * 4] + v[j * 4 + 1] + v[j * 4 + 2] + v[j * 4 + 3];
        }
#pragma unroll
        for (int m = 1; m < 32; m <<= 1) s += __shfl_xor(s, m, 64);
        float mean = s * (1.f / 256.f);
        float q = 0.f;
#pragma unroll
        for (int i = 0; i < 8; ++i) { v[i] -= mean; q += v[i] * v[i]; }
#pragma unroll
        for (int m = 1; m < 32; m <<= 1) q += __shfl_xor(q, m, 64);
        float rstd = rsqrtf(q * (1.f / 256.f) + 1e-5f);
        const float* gp = g2 + c8;
        const float* bp = be2 + c8;
        float* op = out + (size_t)n_ln * DMODEL + c8;
#pragma unroll
        for (int j = 0; j < 2; ++j) {
            float4 gv = ((const float4*)gp)[j];
            float4 bev = ((const float4*)bp)[j];
            float4 y;
            y.x = v[j * 4 + 0] * rstd * gv.x + bev.x;
            y.y = v[j * 4 + 1] * rstd * gv.y + bev.y;
            y.z = v[j * 4 + 2] * rstd * gv.z + bev.z;
            y.w = v[j * 4 + 3] * rstd * gv.w + bev.w;
            ((float4*)op)[j] = y;
        }
    }
}

// ---------------------------------------------------------------------------
extern "C" void kernel_launch(void* const* d_in, const int* in_sizes, int n_in,
                              void* d_out, int out_size, void* d_ws, size_t ws_size,
                              hipStream_t stream) {
    const float* x   = (const float*)d_in[0];
    const int*   adj = (const int*)d_in[1];
    const float* Wq  = (const float*)d_in[2];
    const float* Wk  = (const float*)d_in[3];
    const float* Wv  = (const float*)d_in[4];
    const float* bq  = (const float*)d_in[5];
    const float* bk  = (const float*)d_in[6];
    const float* bv  = (const float*)d_in[7];
    const float* Wo  = (const float*)d_in[8];
    const float* bo  = (const float*)d_in[9];
    const float* g1  = (const float*)d_in[10];
    const float* be1 = (const float*)d_in[11];
    const float* W1  = (const float*)d_in[12];
    const float* b1  = (const float*)d_in[13];
    const float* W2  = (const float*)d_in[14];
    const float* b2  = (const float*)d_in[15];
    const float* g2  = (const float*)d_in[16];
    const float* be2 = (const float*)d_in[17];
    float* out = (float*)d_out;

    char* p = (char*)d_ws;
    unsigned* mask = (unsigned*)p; p += (size_t)NROWS * 128 * 4;          //  2 MB
    short* Wb    = (short*)p;      p += (size_t)327680 * 2;               // .64 MB
    short* Qb    = (short*)p;      p += (size_t)NM * 2;                   //  2 MB
    short* Kb    = (short*)p;      p += (size_t)NM * 2;                   //  2 MB
    short* Vtb   = (short*)p;      p += (size_t)NM * 2;                   //  2 MB
    float* Opart = (float*)p;      p += (size_t)2 * NM * 4;               //  8 MB
    float* lpart = (float*)p;      p += (size_t)2 * NROWS * NHEAD * 4;    // .25 MB

    qkvprep_kernel<<<dim3(2976), dim3(256), 0, stream>>>(
        x, Wq, Wk, Wv, bq, bk, bv, adj, mask, Wo, W1, W2, Wb, Qb, Kb, Vtb);
    attn_kernel<<<dim3(2048), dim3(256), 0, stream>>>(Qb, Kb, Vtb, mask, Opart, lpart);
    mega_kernel<<<dim3(256), dim3(512), 0, stream>>>(
        Opart, lpart, x, Wb, Wb + 65536, Wb + 196608,
        bo, g1, be1, b1, b2, g2, be2, out);
}

// Round 13
// 227.904 us; speedup vs baseline: 1.2676x; 1.0196x over previous
//
#include <hip/hip_runtime.h>
#include <hip/hip_bf16.h>

typedef __attribute__((ext_vector_type(4))) float f32x4;
typedef __attribute__((ext_vector_type(8))) short s16x8;

#define NROWS 4096
#define DMODEL 256
#define NHEAD 8
#define HDIM 32
#define PSTRIDE 72     // attn P-scratch row: 144 B, 16B-aligned
#define OSTRIDE 33     // attn sO row
#define M2C 24.0f      // fixed softmax max (log2 domain)
#define NM (NROWS * DMODEL)
// mega-kernel LDS strides
#define SA_S 264
#define SH_S 268
#define SY_S 264
#define SR_S 520

__device__ __forceinline__ short bf16r(float f) {
    union { float f; unsigned u; } v; v.f = f;
    unsigned r = v.u + 0x7fffu + ((v.u >> 16) & 1u);  // RNE
    return (short)(r >> 16);
}

__device__ __forceinline__ float fexp2(float x) {
    float r;
    asm("v_exp_f32 %0, %1" : "=v"(r) : "v"(x));
    return r;
}

__device__ __forceinline__ unsigned pk_bf16(float a, float b) {
#if __has_builtin(__builtin_amdgcn_cvt_pk_bf16_f32)
    typedef __bf16 bf2 __attribute__((ext_vector_type(2)));
    union { bf2 h; unsigned u; } c;
    c.h = __builtin_amdgcn_cvt_pk_bf16_f32(a, b);
    return c.u;
#else
    return (unsigned)(unsigned short)bf16r(a) | ((unsigned)(unsigned short)bf16r(b) << 16);
#endif
}

__device__ __forceinline__ s16x8 pack8(float4 a, float4 b) {
    s16x8 r;
    r[0] = bf16r(a.x); r[1] = bf16r(a.y); r[2] = bf16r(a.z); r[3] = bf16r(a.w);
    r[4] = bf16r(b.x); r[5] = bf16r(b.y); r[6] = bf16r(b.z); r[7] = bf16r(b.w);
    return r;
}

// ---------------------------------------------------------------------------
// Dispatch 1 (fused): blocks [0,768): QKV GEMM (f32 weights, inline pack);
// V written PRE-SWIZZLED in MFMA A-frag order: Vswz[h][ktile][hdh*2+kh]
// [lane*8+j] so attn's V loads are base+lane*16B (fully coalesced).
// [768,2816): adj -> bitmask. [2816,2976): pack Wo/W1/W2 to bf16.
__global__ __launch_bounds__(256) void qkvprep_kernel(
        const float* __restrict__ X,
        const float* __restrict__ Wq, const float* __restrict__ Wk,
        const float* __restrict__ Wv,
        const float* __restrict__ bq, const float* __restrict__ bk,
        const float* __restrict__ bv,
        const int* __restrict__ adj, unsigned* __restrict__ mask,
        const float* __restrict__ Wo, const float* __restrict__ W1,
        const float* __restrict__ W2, short* __restrict__ Wb,
        short* __restrict__ Qb, short* __restrict__ Kb,
        short* __restrict__ Vswz) {
    __shared__ short sT[64 * 72];   // V-tile staging [hd_local][key_local]
    const int b = blockIdx.x;
    const int tid = threadIdx.x;
    const int lane = tid & 63;
    if (b < 768) {
        const int wv = tid >> 6;
        const int quad = lane >> 4, col = lane & 15;
        const int bx = b & 63, by = b >> 6;           // by 0..11
        const int o0 = by * 64;                        // 0..704
        const int z = o0 >> 8;
        const float* Wsrc = (z == 0) ? Wq : (z == 1 ? Wk : Wv);
        const float* bias = (z == 0) ? bq : (z == 1 ? bk : bv);
        const int ow0 = o0 & 255;
        const int n0 = bx * 64 + wv * 16;
        const float QSC = 0.25505653437397888f;        // log2e / sqrt(32)

        f32x4 zero = {0.f, 0.f, 0.f, 0.f};
        f32x4 acc[4] = {zero, zero, zero, zero};
        const float* ap = X + (size_t)(n0 + col) * DMODEL + quad * 8;
#pragma unroll
        for (int k0 = 0; k0 < DMODEL; k0 += 32) {
            float4 a0 = *(const float4*)(ap + k0);
            float4 a1 = *(const float4*)(ap + k0 + 4);
            s16x8 af = pack8(a0, a1);
#pragma unroll
            for (int t = 0; t < 4; ++t) {
                const float* wp = Wsrc + (size_t)(ow0 + t * 16 + col) * DMODEL + quad * 8 + k0;
                s16x8 bf = pack8(*(const float4*)wp, *(const float4*)(wp + 4));
                acc[t] = __builtin_amdgcn_mfma_f32_16x16x32_bf16(af, bf, acc[t], 0, 0, 0);
            }
        }
        if (z != 2) {
#pragma unroll
            for (int t = 0; t < 4; ++t) {
                const int oo = ow0 + t * 16 + col;
                float bvv = bias[oo];
#pragma unroll
                for (int r = 0; r < 4; ++r) {
                    int n = n0 + quad * 4 + r;
                    float v = acc[t][r] + bvv;
                    if (z == 0) Qb[(size_t)n * DMODEL + oo] = bf16r(v * QSC);
                    else        Kb[(size_t)(oo >> 5) * NROWS * HDIM + (size_t)n * HDIM + (oo & 31)] = bf16r(v);
                }
            }
        } else {
            // V: stage [hd_local 0..63][key_local 0..63] tile in LDS.
#pragma unroll
            for (int t = 0; t < 4; ++t) {
                const int oot = t * 16 + col;
                float bvv = bias[ow0 + oot];
#pragma unroll
                for (int r = 0; r < 4; ++r) {
                    int nn = wv * 16 + quad * 4 + r;
                    sT[oot * 72 + nn] = bf16r(acc[t][r] + bvv);
                }
            }
            __syncthreads();
            // Emit swizzled frags: frag f = (lh, hdh, kh); element (lane L, j)
            // = V^T[lh*32+hdh*16+(L&15)][kh*32+(L>>4)*8+j]. 32 threads/frag,
            // 2 lanes (32 B) each: contiguous global stores.
            const int f = tid >> 5;                 // 0..7
            const int lh = f >> 2, hdh = (f >> 1) & 1, kh = f & 1;
            const int L0 = (tid & 31) * 2;
            const int hgl = (ow0 >> 5) + lh;        // global head
            short* dst = Vswz + (((size_t)(hgl * 64 + bx) * 4 + hdh * 2 + kh) * 512);
#pragma unroll
            for (int e = 0; e < 2; ++e) {
                int L = L0 + e;
                int hd_local = lh * 32 + hdh * 16 + (L & 15);
                int key_local = kh * 32 + ((L >> 4) * 8);
                s16x8 v = *(const s16x8*)&sT[hd_local * 72 + key_local];
                *(s16x8*)(dst + L * 8) = v;
            }
        }
    } else if (b < 2816) {
        const int waveid = (b - 768) * 4 + (tid >> 6);  // 0..8191
        int4 av[8];
        int rows[8], segs[8];
#pragma unroll
        for (int i = 0; i < 8; ++i) {
            const int task = waveid + i * 8192;          // 0..65535
            rows[i] = task >> 4; segs[i] = task & 15;
            av[i] = *(const int4*)(adj + (size_t)rows[i] * NROWS + segs[i] * 256 + lane * 4);
        }
#pragma unroll
        for (int i = 0; i < 8; ++i) {
            const int row = rows[i];
            const int c0 = segs[i] * 256 + lane * 4;
            unsigned nib = (unsigned)(av[i].x > 0 || c0 == row)
                         | ((unsigned)(av[i].y > 0 || c0 + 1 == row) << 1)
                         | ((unsigned)(av[i].z > 0 || c0 + 2 == row) << 2)
                         | ((unsigned)(av[i].w > 0 || c0 + 3 == row) << 3);
            unsigned v = nib << ((lane & 7) * 4);
            v |= __shfl_xor((int)v, 1, 64);
            v |= __shfl_xor((int)v, 2, 64);
            v |= __shfl_xor((int)v, 4, 64);
            if ((lane & 7) == 0)
                mask[row * 128 + segs[i] * 8 + (lane >> 3)] = v;
        }
    } else {
        int i = (b - 2816) * 2048 + tid * 8;
        const float* src; int off;
        if (i < 65536)       { src = Wo; off = i; }
        else if (i < 196608) { src = W1; off = i - 65536; }
        else                 { src = W2; off = i - 196608; }
        float4 a = *(const float4*)(src + off);
        float4 c = *(const float4*)(src + off + 4);
        *(s16x8*)(Wb + i) = pack8(a, c);
    }
}

// ---------------------------------------------------------------------------
// Dispatch 2: flash attention (round-8 structure: ones-MFMA row-sums,
// unroll 2) with COALESCED V-frag loads from the swizzled layout.
__global__ __launch_bounds__(256) void attn_kernel(const short* __restrict__ Qb,
                                                   const short* __restrict__ Kb,
                                                   const short* __restrict__ Vswz,
                                                   const unsigned* __restrict__ mask,
                                                   float* __restrict__ Opart,
                                                   float* __restrict__ lpart) {
    __shared__ union {
        short sP[2][16 * PSTRIDE];
        float sO[HDIM][OSTRIDE];
    } u[4];
    __shared__ float sl[4][32];

    const int tid = threadIdx.x;
    const int wv = tid >> 6, lane = tid & 63;
    const int quad = lane >> 4, col = lane & 15;
    const int khalf = blockIdx.x & 1;
    const int h = (blockIdx.x >> 1) & 7;
    const int q0 = (blockIdx.x >> 4) * 32;
    const int kw = khalf * 2048 + wv * 512;

    s16x8 qf[2];
    qf[0] = *(const s16x8*)(Qb + (size_t)(q0 + col) * DMODEL + h * HDIM + quad * 8);
    qf[1] = *(const s16x8*)(Qb + (size_t)(q0 + 16 + col) * DMODEL + h * HDIM + quad * 8);

    const short* kp = Kb + (size_t)h * NROWS * HDIM + (size_t)(kw + col) * HDIM + quad * 8;
    const short* vbase = Vswz + ((size_t)(h * 64 + (kw >> 6)) * 4) * 512 + lane * 8;
    const unsigned* mp0 = mask + (size_t)(q0 + col) * 128 + (kw >> 5);
    const unsigned* mp1 = mp0 + 16 * 128;

    const short onev = (col == 0) ? (short)0x3F80 : (short)0;
    const s16x8 ones = {onev, onev, onev, onev, onev, onev, onev, onev};

    f32x4 zero = {0.f, 0.f, 0.f, 0.f};
    f32x4 acc[2][2] = {{zero, zero}, {zero, zero}};
    f32x4 lacc[2] = {zero, zero};
    const f32x4 cinit = {-M2C, -M2C, -M2C, -M2C};

#pragma unroll 2
    for (int it = 0; it < 8; ++it) {
        const short* k = kp + it * 64 * HDIM;
        s16x8 kf0 = *(const s16x8*)(k);
        s16x8 kf1 = *(const s16x8*)(k + 16 * HDIM);
        s16x8 kf2 = *(const s16x8*)(k + 32 * HDIM);
        s16x8 kf3 = *(const s16x8*)(k + 48 * HDIM);
        uint2 w0 = *(const uint2*)(mp0 + it * 2);
        uint2 w1 = *(const uint2*)(mp1 + it * 2);
        const short* vb = vbase + it * 4 * 512;
        s16x8 vf00 = *(const s16x8*)(vb);             // hd 0-15,  keys 0-31
        s16x8 vf01 = *(const s16x8*)(vb + 512);       // hd 0-15,  keys 32-63
        s16x8 vf10 = *(const s16x8*)(vb + 1024);      // hd 16-31, keys 0-31
        s16x8 vf11 = *(const s16x8*)(vb + 1536);      // hd 16-31, keys 32-63

#pragma unroll
        for (int qs = 0; qs < 2; ++qs) {
            unsigned wlo = (qs ? w1.x : w0.x) >> (quad * 4);
            unsigned whi = (qs ? w1.y : w0.y) >> (quad * 4);
            f32x4 st[4];
            st[0] = __builtin_amdgcn_mfma_f32_16x16x32_bf16(kf0, qf[qs], cinit, 0, 0, 0);
            st[1] = __builtin_amdgcn_mfma_f32_16x16x32_bf16(kf1, qf[qs], cinit, 0, 0, 0);
            st[2] = __builtin_amdgcn_mfma_f32_16x16x32_bf16(kf2, qf[qs], cinit, 0, 0, 0);
            st[3] = __builtin_amdgcn_mfma_f32_16x16x32_bf16(kf3, qf[qs], cinit, 0, 0, 0);

            float p[4][4];
#pragma unroll
            for (int t = 0; t < 4; ++t) {
                unsigned wm = (t < 2) ? wlo : whi;
#pragma unroll
                for (int r = 0; r < 4; ++r) {
                    float e = fexp2(st[t][r]);
                    bool ok = (wm & (1u << ((t & 1) * 16 + r))) != 0u;
                    p[t][r] = ok ? e : 0.f;
                }
            }

            short* pb = &u[wv].sP[qs][0];
#pragma unroll
            for (int t = 0; t < 4; ++t) {
                uint2 pr;
                pr.x = pk_bf16(p[t][0], p[t][1]);
                pr.y = pk_bf16(p[t][2], p[t][3]);
                *(uint2*)(pb + col * PSTRIDE + t * 16 + quad * 4) = pr;
            }
            s16x8 pb0 = *(const s16x8*)(pb + col * PSTRIDE + quad * 8);
            s16x8 pb1 = *(const s16x8*)(pb + col * PSTRIDE + 32 + quad * 8);

            acc[qs][0] = __builtin_amdgcn_mfma_f32_16x16x32_bf16(vf00, pb0, acc[qs][0], 0, 0, 0);
            acc[qs][0] = __builtin_amdgcn_mfma_f32_16x16x32_bf16(vf01, pb1, acc[qs][0], 0, 0, 0);
            acc[qs][1] = __builtin_amdgcn_mfma_f32_16x16x32_bf16(vf10, pb0, acc[qs][1], 0, 0, 0);
            acc[qs][1] = __builtin_amdgcn_mfma_f32_16x16x32_bf16(vf11, pb1, acc[qs][1], 0, 0, 0);
            lacc[qs] = __builtin_amdgcn_mfma_f32_16x16x32_bf16(ones, pb0, lacc[qs], 0, 0, 0);
            lacc[qs] = __builtin_amdgcn_mfma_f32_16x16x32_bf16(ones, pb1, lacc[qs], 0, 0, 0);
        }
    }

#pragma unroll
    for (int qs = 0; qs < 2; ++qs) {
        if (lane < 16) sl[wv][qs * 16 + col] = lacc[qs][0];
#pragma unroll
        for (int rr = 0; rr < 4; ++rr) {
            u[wv].sO[quad * 4 + rr][qs * 16 + col]      = acc[qs][0][rr];
            u[wv].sO[16 + quad * 4 + rr][qs * 16 + col] = acc[qs][1][rr];
        }
    }
    __syncthreads();

    const int q = tid >> 3, hd0 = (tid & 7) * 4;
    float l = sl[0][q] + sl[1][q] + sl[2][q] + sl[3][q];
    float4 ov;
    ov.x = u[0].sO[hd0][q]     + u[1].sO[hd0][q]     + u[2].sO[hd0][q]     + u[3].sO[hd0][q];
    ov.y = u[0].sO[hd0 + 1][q] + u[1].sO[hd0 + 1][q] + u[2].sO[hd0 + 1][q] + u[3].sO[hd0 + 1][q];
    ov.z = u[0].sO[hd0 + 2][q] + u[1].sO[hd0 + 2][q] + u[2].sO[hd0 + 2][q] + u[3].sO[hd0 + 2][q];
    ov.w = u[0].sO[hd0 + 3][q] + u[1].sO[hd0 + 3][q] + u[2].sO[hd0 + 3][q] + u[3].sO[hd0 + 3][q];
    *(float4*)(Opart + (size_t)khalf * NM + (size_t)(q0 + q) * DMODEL + h * HDIM + hd0) = ov;
    if ((tid & 7) == 0) lpart[khalf * NROWS * NHEAD + (q0 + q) * NHEAD + h] = l;
}

// ---------------------------------------------------------------------------
// Dispatch 3: post-attention chain per 16-row stripe, 512 threads/block.
__global__ __launch_bounds__(512) void mega_kernel(
        const float* __restrict__ Opart, const float* __restrict__ lpart,
        const float* __restrict__ X,
        const short* __restrict__ Wob, const short* __restrict__ W1b,
        const short* __restrict__ W2b,
        const float* __restrict__ bo,
        const float* __restrict__ g1, const float* __restrict__ be1,
        const float* __restrict__ b1, const float* __restrict__ b2,
        const float* __restrict__ g2, const float* __restrict__ be2,
        float* __restrict__ out) {
    __shared__ union { short sA[16 * SA_S]; short sR[16 * SR_S]; } uu;
    __shared__ float sH[16 * SH_S];
    __shared__ short sY[16 * SY_S];

    const int tid = threadIdx.x;
    const int wv = tid >> 6, lane = tid & 63;
    const int quad = lane >> 4, col = lane & 15;
    const int n0 = blockIdx.x * 16;
    const int rr_ = tid >> 5, c8 = (tid & 31) * 8;
    const int n_ln = n0 + rr_;
    f32x4 zero = {0.f, 0.f, 0.f, 0.f};

    // ---- Stage A: normalized merged O -> sA (bf16) ----
    {
        const int head = c8 >> 5;
        float li = 1.f / (lpart[(size_t)n_ln * NHEAD + head] +
                          lpart[(size_t)NROWS * NHEAD + (size_t)n_ln * NHEAD + head]);
        const float* p0 = Opart + (size_t)n_ln * DMODEL + c8;
        const float* p1 = p0 + NM;
        float4 a0 = ((const float4*)p0)[0], a1 = ((const float4*)p0)[1];
        float4 b0 = ((const float4*)p1)[0], b1v = ((const float4*)p1)[1];
        s16x8 w;
        *((unsigned*)&w + 0) = pk_bf16((a0.x + b0.x) * li, (a0.y + b0.y) * li);
        *((unsigned*)&w + 1) = pk_bf16((a0.z + b0.z) * li, (a0.w + b0.w) * li);
        *((unsigned*)&w + 2) = pk_bf16((a1.x + b1v.x) * li, (a1.y + b1v.y) * li);
        *((unsigned*)&w + 3) = pk_bf16((a1.z + b1v.z) * li, (a1.w + b1v.w) * li);
        *(s16x8*)&uu.sA[rr_ * SA_S + c8] = w;
    }
    __syncthreads();

    // ---- Stage A2: h = Anorm · Wo^T + bo (wave: 16 x 32) ----
    {
        const int o0 = wv * 32;
        f32x4 acc[2] = {zero, zero};
#pragma unroll
        for (int k0 = 0; k0 < DMODEL; k0 += 32) {
            s16x8 af = *(const s16x8*)&uu.sA[col * SA_S + k0 + quad * 8];
#pragma unroll
            for (int t = 0; t < 2; ++t) {
                s16x8 bf = *(const s16x8*)(Wob + (size_t)(o0 + t * 16 + col) * DMODEL + k0 + quad * 8);
                acc[t] = __builtin_amdgcn_mfma_f32_16x16x32_bf16(af, bf, acc[t], 0, 0, 0);
            }
        }
#pragma unroll
        for (int t = 0; t < 2; ++t) {
            int o = o0 + t * 16 + col;
            float bv = bo[o];
#pragma unroll
            for (int r = 0; r < 4; ++r)
                sH[(quad * 4 + r) * SH_S + o] = acc[t][r] + bv;
        }
    }
    __syncthreads();

    // ---- LN1 ----
    float y1v[8];
    {
        const float* xp = X + (size_t)n_ln * DMODEL + c8;
        float v[8];
        float s = 0.f;
#pragma unroll
        for (int j = 0; j < 2; ++j) {
            float4 xv = ((const float4*)xp)[j];
            float4 hv = *(const float4*)&sH[rr_ * SH_S + c8 + j * 4];
            v[j * 4 + 0] = xv.x + hv.x; v[j * 4 + 1] = xv.y + hv.y;
            v[j * 4 + 2] = xv.z + hv.z; v[j * 4 + 3] = xv.w + hv.w;
            s += v[j * 4] + v[j * 4 + 1] + v[j * 4 + 2] + v[j * 4 + 3];
        }
#pragma unroll
        for (int m = 1; m < 32; m <<= 1) s += __shfl_xor(s, m, 64);
        float mean = s * (1.f / 256.f);
        float q = 0.f;
#pragma unroll
        for (int i = 0; i < 8; ++i) { v[i] -= mean; q += v[i] * v[i]; }
#pragma unroll
        for (int m = 1; m < 32; m <<= 1) q += __shfl_xor(q, m, 64);
        float rstd = rsqrtf(q * (1.f / 256.f) + 1e-5f);
        const float* gp = g1 + c8;
        const float* bp = be1 + c8;
        s16x8 w;
#pragma unroll
        for (int j = 0; j < 2; ++j) {
            float4 gv = ((const float4*)gp)[j];
            float4 bev = ((const float4*)bp)[j];
            float a0 = v[j * 4 + 0] * rstd * gv.x + bev.x;
            float a1 = v[j * 4 + 1] * rstd * gv.y + bev.y;
            float a2 = v[j * 4 + 2] * rstd * gv.z + bev.z;
            float a3 = v[j * 4 + 3] * rstd * gv.w + bev.w;
            y1v[j * 4 + 0] = a0; y1v[j * 4 + 1] = a1;
            y1v[j * 4 + 2] = a2; y1v[j * 4 + 3] = a3;
            *((unsigned*)&w + j * 2 + 0) = pk_bf16(a0, a1);
            *((unsigned*)&w + j * 2 + 1) = pk_bf16(a2, a3);
        }
        *(s16x8*)&sY[rr_ * SY_S + c8] = w;
    }
    __syncthreads();

    // ---- Stage B: relu(y1 · W1^T + b1) -> sR (wave: 16 x 64) ----
    {
        const int o0 = wv * 64;
        f32x4 acc[4] = {zero, zero, zero, zero};
#pragma unroll
        for (int k0 = 0; k0 < DMODEL; k0 += 32) {
            s16x8 af = *(const s16x8*)&sY[col * SY_S + k0 + quad * 8];
#pragma unroll
            for (int t = 0; t < 4; ++t) {
                s16x8 bf = *(const s16x8*)(W1b + (size_t)(o0 + t * 16 + col) * DMODEL + k0 + quad * 8);
                acc[t] = __builtin_amdgcn_mfma_f32_16x16x32_bf16(af, bf, acc[t], 0, 0, 0);
            }
        }
#pragma unroll
        for (int t = 0; t < 4; ++t) {
            int o = o0 + t * 16 + col;
            float bv = b1[o];
#pragma unroll
            for (int r = 0; r < 4; ++r)
                uu.sR[(quad * 4 + r) * SR_S + o] = bf16r(fmaxf(acc[t][r] + bv, 0.f));
        }
    }
    __syncthreads();

    // ---- Stage C: t2 = r · W2^T + b2 (wave: 16 x 32, K=512) -> sH ----
    {
        const int o0 = wv * 32;
        f32x4 acc[2] = {zero, zero};
#pragma unroll
        for (int k0 = 0; k0 < 512; k0 += 32) {
            s16x8 af = *(const s16x8*)&uu.sR[col * SR_S + k0 + quad * 8];
#pragma unroll
            for (int t = 0; t < 2; ++t) {
                s16x8 bf = *(const s16x8*)(W2b + (size_t)(o0 + t * 16 + col) * 512 + k0 + quad * 8);
                acc[t] = __builtin_amdgcn_mfma_f32_16x16x32_bf16(af, bf, acc[t], 0, 0, 0);
            }
        }
#pragma unroll
        for (int t = 0; t < 2; ++t) {
            int o = o0 + t * 16 + col;
            float bv = b2[o];
#pragma unroll
            for (int r = 0; r < 4; ++r)
                sH[(quad * 4 + r) * SH_S + o] = acc[t][r] + bv;
        }
    }
    __syncthreads();

    // ---- LN2 ----
    {
        float v[8];
        float s = 0.f;
#pragma unroll
        for (int j = 0; j < 2; ++j) {
            float4 hv = *(const float4*)&sH[rr_ * SH_S + c8 + j * 4];
            v[j * 4 + 0] = y1v[j * 4 + 0] + hv.x; v[j * 4 + 1] = y1v[j * 4 + 1] + hv.y;
            v[j * 4 + 2] = y1v[j * 4 + 2] + hv.z; v[j * 4 + 3] = y1v[j * 4 + 3] + hv.w;
            s += v[j * 4] + v[j * 4 + 1] + v[j * 4 + 2] + v[j * 4 + 3];
        }
#pragma unroll
        for (int m = 1; m < 32; m <<= 1) s += __shfl_xor(s, m, 64);
        float mean = s * (1.f / 256.f);
        float q = 0.f;
#pragma unroll
        for (int i = 0; i < 8; ++i) { v[i] -= mean; q += v[i] * v[i]; }
#pragma unroll
        for (int m = 1; m < 32; m <<= 1) q += __shfl_xor(q, m, 64);
        float rstd = rsqrtf(q * (1.f / 256.f) + 1e-5f);
        const float* gp = g2 + c8;
        const float* bp = be2 + c8;
        float* op = out + (size_t)n_ln * DMODEL + c8;
#pragma unroll
        for (int j = 0; j < 2; ++j) {
            float4 gv = ((const float4*)gp)[j];
            float4 bev = ((const float4*)bp)[j];
            float4 y;
            y.x = v[j * 4 + 0] * rstd * gv.x + bev.x;
            y.y = v[j * 4 + 1] * rstd * gv.y + bev.y;
            y.z = v[j * 4 + 2] * rstd * gv.z + bev.z;
            y.w = v[j * 4 + 3] * rstd * gv.w + bev.w;
            ((float4*)op)[j] = y;
        }
    }
}

// ---------------------------------------------------------------------------
extern "C" void kernel_launch(void* const* d_in, const int* in_sizes, int n_in,
                              void* d_out, int out_size, void* d_ws, size_t ws_size,
                              hipStream_t stream) {
    const float* x   = (const float*)d_in[0];
    const int*   adj = (const int*)d_in[1];
    const float* Wq  = (const float*)d_in[2];
    const float* Wk  = (const float*)d_in[3];
    const float* Wv  = (const float*)d_in[4];
    const float* bq  = (const float*)d_in[5];
    const float* bk  = (const float*)d_in[6];
    const float* bv  = (const float*)d_in[7];
    const float* Wo  = (const float*)d_in[8];
    const float* bo  = (const float*)d_in[9];
    const float* g1  = (const float*)d_in[10];
    const float* be1 = (const float*)d_in[11];
    const float* W1  = (const float*)d_in[12];
    const float* b1  = (const float*)d_in[13];
    const float* W2  = (const float*)d_in[14];
    const float* b2  = (const float*)d_in[15];
    const float* g2  = (const float*)d_in[16];
    const float* be2 = (const float*)d_in[17];
    float* out = (float*)d_out;

    char* p = (char*)d_ws;
    unsigned* mask = (unsigned*)p; p += (size_t)NROWS * 128 * 4;          //  2 MB
    short* Wb    = (short*)p;      p += (size_t)327680 * 2;               // .64 MB
    short* Qb    = (short*)p;      p += (size_t)NM * 2;                   //  2 MB
    short* Kb    = (short*)p;      p += (size_t)NM * 2;                   //  2 MB
    short* Vswz  = (short*)p;      p += (size_t)NM * 2;                   //  2 MB
    float* Opart = (float*)p;      p += (size_t)2 * NM * 4;               //  8 MB
    float* lpart = (float*)p;      p += (size_t)2 * NROWS * NHEAD * 4;    // .25 MB

    qkvprep_kernel<<<dim3(2976), dim3(256), 0, stream>>>(
        x, Wq, Wk, Wv, bq, bk, bv, adj, mask, Wo, W1, W2, Wb, Qb, Kb, Vswz);
    attn_kernel<<<dim3(2048), dim3(256), 0, stream>>>(Qb, Kb, Vswz, mask, Opart, lpart);
    mega_kernel<<<dim3(256), dim3(512), 0, stream>>>(
        Opart, lpart, x, Wb, Wb + 65536, Wb + 196608,
        bo, g1, be1, b1, b2, g2, be2, out);
}

// Round 14
// 225.434 us; speedup vs baseline: 1.2815x; 1.0110x over previous
//
#include <hip/hip_runtime.h>
#include <hip/hip_bf16.h>

typedef __attribute__((ext_vector_type(4))) float f32x4;
typedef __attribute__((ext_vector_type(8))) short s16x8;

#define NROWS 4096
#define DMODEL 256
#define NHEAD 8
#define HDIM 32
#define PSTRIDE 72     // attn P-scratch row: 144 B, 16B-aligned
#define OSTRIDE 33     // attn sO row
#define M2C 24.0f      // fixed softmax max (log2 domain)
#define NM (NROWS * DMODEL)
// mega-kernel LDS strides
#define SH_S 268
#define SY_S 264
#define SR_S 520

__device__ __forceinline__ short bf16r(float f) {
    union { float f; unsigned u; } v; v.f = f;
    unsigned r = v.u + 0x7fffu + ((v.u >> 16) & 1u);  // RNE
    return (short)(r >> 16);
}

__device__ __forceinline__ float fexp2(float x) {
    float r;
    asm("v_exp_f32 %0, %1" : "=v"(r) : "v"(x));
    return r;
}

__device__ __forceinline__ unsigned pk_bf16(float a, float b) {
#if __has_builtin(__builtin_amdgcn_cvt_pk_bf16_f32)
    typedef __bf16 bf2 __attribute__((ext_vector_type(2)));
    union { bf2 h; unsigned u; } c;
    c.h = __builtin_amdgcn_cvt_pk_bf16_f32(a, b);
    return c.u;
#else
    return (unsigned)(unsigned short)bf16r(a) | ((unsigned)(unsigned short)bf16r(b) << 16);
#endif
}

__device__ __forceinline__ s16x8 pack8(float4 a, float4 b) {
    s16x8 r;
    r[0] = bf16r(a.x); r[1] = bf16r(a.y); r[2] = bf16r(a.z); r[3] = bf16r(a.w);
    r[4] = bf16r(b.x); r[5] = bf16r(b.y); r[6] = bf16r(b.z); r[7] = bf16r(b.w);
    return r;
}

// ---------------------------------------------------------------------------
// Dispatch 1 (fused): blocks [0,768): QKV GEMM (f32 weights, inline pack);
// V written PRE-SWIZZLED in MFMA A-frag order (coalesced attn loads).
// [768,2816): adj -> bitmask. [2816,2976): pack Wo/W1/W2 to bf16.
__global__ __launch_bounds__(256) void qkvprep_kernel(
        const float* __restrict__ X,
        const float* __restrict__ Wq, const float* __restrict__ Wk,
        const float* __restrict__ Wv,
        const float* __restrict__ bq, const float* __restrict__ bk,
        const float* __restrict__ bv,
        const int* __restrict__ adj, unsigned* __restrict__ mask,
        const float* __restrict__ Wo, const float* __restrict__ W1,
        const float* __restrict__ W2, short* __restrict__ Wb,
        short* __restrict__ Qb, short* __restrict__ Kb,
        short* __restrict__ Vswz) {
    __shared__ short sT[64 * 72];   // V-tile staging [hd_local][key_local]
    const int b = blockIdx.x;
    const int tid = threadIdx.x;
    const int lane = tid & 63;
    if (b < 768) {
        const int wv = tid >> 6;
        const int quad = lane >> 4, col = lane & 15;
        const int bx = b & 63, by = b >> 6;           // by 0..11
        const int o0 = by * 64;                        // 0..704
        const int z = o0 >> 8;
        const float* Wsrc = (z == 0) ? Wq : (z == 1 ? Wk : Wv);
        const float* bias = (z == 0) ? bq : (z == 1 ? bk : bv);
        const int ow0 = o0 & 255;
        const int n0 = bx * 64 + wv * 16;
        const float QSC = 0.25505653437397888f;        // log2e / sqrt(32)

        f32x4 zero = {0.f, 0.f, 0.f, 0.f};
        f32x4 acc[4] = {zero, zero, zero, zero};
        const float* ap = X + (size_t)(n0 + col) * DMODEL + quad * 8;
#pragma unroll
        for (int k0 = 0; k0 < DMODEL; k0 += 32) {
            float4 a0 = *(const float4*)(ap + k0);
            float4 a1 = *(const float4*)(ap + k0 + 4);
            s16x8 af = pack8(a0, a1);
#pragma unroll
            for (int t = 0; t < 4; ++t) {
                const float* wp = Wsrc + (size_t)(ow0 + t * 16 + col) * DMODEL + quad * 8 + k0;
                s16x8 bf = pack8(*(const float4*)wp, *(const float4*)(wp + 4));
                acc[t] = __builtin_amdgcn_mfma_f32_16x16x32_bf16(af, bf, acc[t], 0, 0, 0);
            }
        }
        if (z != 2) {
#pragma unroll
            for (int t = 0; t < 4; ++t) {
                const int oo = ow0 + t * 16 + col;
                float bvv = bias[oo];
#pragma unroll
                for (int r = 0; r < 4; ++r) {
                    int n = n0 + quad * 4 + r;
                    float v = acc[t][r] + bvv;
                    if (z == 0) Qb[(size_t)n * DMODEL + oo] = bf16r(v * QSC);
                    else        Kb[(size_t)(oo >> 5) * NROWS * HDIM + (size_t)n * HDIM + (oo & 31)] = bf16r(v);
                }
            }
        } else {
            // V: stage [hd_local 0..63][key_local 0..63] tile in LDS.
#pragma unroll
            for (int t = 0; t < 4; ++t) {
                const int oot = t * 16 + col;
                float bvv = bias[ow0 + oot];
#pragma unroll
                for (int r = 0; r < 4; ++r) {
                    int nn = wv * 16 + quad * 4 + r;
                    sT[oot * 72 + nn] = bf16r(acc[t][r] + bvv);
                }
            }
            __syncthreads();
            // Emit swizzled frags: frag f = (lh, hdh, kh); element (lane L, j)
            // = V^T[lh*32+hdh*16+(L&15)][kh*32+(L>>4)*8+j].
            const int f = tid >> 5;                 // 0..7
            const int lh = f >> 2, hdh = (f >> 1) & 1, kh = f & 1;
            const int L0 = (tid & 31) * 2;
            const int hgl = (ow0 >> 5) + lh;        // global head
            short* dst = Vswz + (((size_t)(hgl * 64 + bx) * 4 + hdh * 2 + kh) * 512);
#pragma unroll
            for (int e = 0; e < 2; ++e) {
                int L = L0 + e;
                int hd_local = lh * 32 + hdh * 16 + (L & 15);
                int key_local = kh * 32 + ((L >> 4) * 8);
                s16x8 v = *(const s16x8*)&sT[hd_local * 72 + key_local];
                *(s16x8*)(dst + L * 8) = v;
            }
        }
    } else if (b < 2816) {
        const int waveid = (b - 768) * 4 + (tid >> 6);  // 0..8191
        int4 av[8];
        int rows[8], segs[8];
#pragma unroll
        for (int i = 0; i < 8; ++i) {
            const int task = waveid + i * 8192;          // 0..65535
            rows[i] = task >> 4; segs[i] = task & 15;
            av[i] = *(const int4*)(adj + (size_t)rows[i] * NROWS + segs[i] * 256 + lane * 4);
        }
#pragma unroll
        for (int i = 0; i < 8; ++i) {
            const int row = rows[i];
            const int c0 = segs[i] * 256 + lane * 4;
            unsigned nib = (unsigned)(av[i].x > 0 || c0 == row)
                         | ((unsigned)(av[i].y > 0 || c0 + 1 == row) << 1)
                         | ((unsigned)(av[i].z > 0 || c0 + 2 == row) << 2)
                         | ((unsigned)(av[i].w > 0 || c0 + 3 == row) << 3);
            unsigned v = nib << ((lane & 7) * 4);
            v |= __shfl_xor((int)v, 1, 64);
            v |= __shfl_xor((int)v, 2, 64);
            v |= __shfl_xor((int)v, 4, 64);
            if ((lane & 7) == 0)
                mask[row * 128 + segs[i] * 8 + (lane >> 3)] = v;
        }
    } else {
        int i = (b - 2816) * 2048 + tid * 8;
        const float* src; int off;
        if (i < 65536)       { src = Wo; off = i; }
        else if (i < 196608) { src = W1; off = i - 65536; }
        else                 { src = W2; off = i - 196608; }
        float4 a = *(const float4*)(src + off);
        float4 c = *(const float4*)(src + off + 4);
        *(s16x8*)(Wb + i) = pack8(a, c);
    }
}

// ---------------------------------------------------------------------------
// Dispatch 2: flash attention. Block = (32 q, head), grid 1024 (single
// balanced scheduling round); wave w owns keys [w*1024, +1024), 16 iters.
// All 4 key-partitions in-block -> normalize HERE, write bf16 Omb (2 MB vs
// round-13's 16 MB f32 partial-sum round-trip). V loads coalesced (swizzled).
__global__ __launch_bounds__(256) void attn_kernel(const short* __restrict__ Qb,
                                                   const short* __restrict__ Kb,
                                                   const short* __restrict__ Vswz,
                                                   const unsigned* __restrict__ mask,
                                                   short* __restrict__ Om) {
    __shared__ union {
        short sP[2][16 * PSTRIDE];
        float sO[HDIM][OSTRIDE];
    } u[4];
    __shared__ float sl[4][32];

    const int tid = threadIdx.x;
    const int wv = tid >> 6, lane = tid & 63;
    const int quad = lane >> 4, col = lane & 15;
    const int h = blockIdx.x & 7;
    const int q0 = (blockIdx.x >> 3) * 32;
    const int kw = wv * 1024;

    s16x8 qf[2];
    qf[0] = *(const s16x8*)(Qb + (size_t)(q0 + col) * DMODEL + h * HDIM + quad * 8);
    qf[1] = *(const s16x8*)(Qb + (size_t)(q0 + 16 + col) * DMODEL + h * HDIM + quad * 8);

    const short* kp = Kb + (size_t)h * NROWS * HDIM + (size_t)(kw + col) * HDIM + quad * 8;
    const short* vbase = Vswz + ((size_t)(h * 64 + (kw >> 6)) * 4) * 512 + lane * 8;
    const unsigned* mp0 = mask + (size_t)(q0 + col) * 128 + (kw >> 5);
    const unsigned* mp1 = mp0 + 16 * 128;

    const short onev = (col == 0) ? (short)0x3F80 : (short)0;
    const s16x8 ones = {onev, onev, onev, onev, onev, onev, onev, onev};

    f32x4 zero = {0.f, 0.f, 0.f, 0.f};
    f32x4 acc[2][2] = {{zero, zero}, {zero, zero}};
    f32x4 lacc[2] = {zero, zero};
    const f32x4 cinit = {-M2C, -M2C, -M2C, -M2C};

#pragma unroll 2
    for (int it = 0; it < 16; ++it) {
        const short* k = kp + it * 64 * HDIM;
        s16x8 kf0 = *(const s16x8*)(k);
        s16x8 kf1 = *(const s16x8*)(k + 16 * HDIM);
        s16x8 kf2 = *(const s16x8*)(k + 32 * HDIM);
        s16x8 kf3 = *(const s16x8*)(k + 48 * HDIM);
        uint2 w0 = *(const uint2*)(mp0 + it * 2);
        uint2 w1 = *(const uint2*)(mp1 + it * 2);
        const short* vb = vbase + it * 4 * 512;
        s16x8 vf00 = *(const s16x8*)(vb);             // hd 0-15,  keys 0-31
        s16x8 vf01 = *(const s16x8*)(vb + 512);       // hd 0-15,  keys 32-63
        s16x8 vf10 = *(const s16x8*)(vb + 1024);      // hd 16-31, keys 0-31
        s16x8 vf11 = *(const s16x8*)(vb + 1536);      // hd 16-31, keys 32-63

#pragma unroll
        for (int qs = 0; qs < 2; ++qs) {
            unsigned wlo = (qs ? w1.x : w0.x) >> (quad * 4);
            unsigned whi = (qs ? w1.y : w0.y) >> (quad * 4);
            f32x4 st[4];
            st[0] = __builtin_amdgcn_mfma_f32_16x16x32_bf16(kf0, qf[qs], cinit, 0, 0, 0);
            st[1] = __builtin_amdgcn_mfma_f32_16x16x32_bf16(kf1, qf[qs], cinit, 0, 0, 0);
            st[2] = __builtin_amdgcn_mfma_f32_16x16x32_bf16(kf2, qf[qs], cinit, 0, 0, 0);
            st[3] = __builtin_amdgcn_mfma_f32_16x16x32_bf16(kf3, qf[qs], cinit, 0, 0, 0);

            float p[4][4];
#pragma unroll
            for (int t = 0; t < 4; ++t) {
                unsigned wm = (t < 2) ? wlo : whi;
#pragma unroll
                for (int r = 0; r < 4; ++r) {
                    float e = fexp2(st[t][r]);
                    bool ok = (wm & (1u << ((t & 1) * 16 + r))) != 0u;
                    p[t][r] = ok ? e : 0.f;
                }
            }

            short* pb = &u[wv].sP[qs][0];
#pragma unroll
            for (int t = 0; t < 4; ++t) {
                uint2 pr;
                pr.x = pk_bf16(p[t][0], p[t][1]);
                pr.y = pk_bf16(p[t][2], p[t][3]);
                *(uint2*)(pb + col * PSTRIDE + t * 16 + quad * 4) = pr;
            }
            s16x8 pb0 = *(const s16x8*)(pb + col * PSTRIDE + quad * 8);
            s16x8 pb1 = *(const s16x8*)(pb + col * PSTRIDE + 32 + quad * 8);

            acc[qs][0] = __builtin_amdgcn_mfma_f32_16x16x32_bf16(vf00, pb0, acc[qs][0], 0, 0, 0);
            acc[qs][0] = __builtin_amdgcn_mfma_f32_16x16x32_bf16(vf01, pb1, acc[qs][0], 0, 0, 0);
            acc[qs][1] = __builtin_amdgcn_mfma_f32_16x16x32_bf16(vf10, pb0, acc[qs][1], 0, 0, 0);
            acc[qs][1] = __builtin_amdgcn_mfma_f32_16x16x32_bf16(vf11, pb1, acc[qs][1], 0, 0, 0);
            lacc[qs] = __builtin_amdgcn_mfma_f32_16x16x32_bf16(ones, pb0, lacc[qs], 0, 0, 0);
            lacc[qs] = __builtin_amdgcn_mfma_f32_16x16x32_bf16(ones, pb1, lacc[qs], 0, 0, 0);
        }
    }

#pragma unroll
    for (int qs = 0; qs < 2; ++qs) {
        if (lane < 16) sl[wv][qs * 16 + col] = lacc[qs][0];
#pragma unroll
        for (int rr = 0; rr < 4; ++rr) {
            u[wv].sO[quad * 4 + rr][qs * 16 + col]      = acc[qs][0][rr];
            u[wv].sO[16 + quad * 4 + rr][qs * 16 + col] = acc[qs][1][rr];
        }
    }
    __syncthreads();

    // merge the 4 key-partitions, normalize, write bf16
    const int q = tid >> 3, hd0 = (tid & 7) * 4;
    float l = sl[0][q] + sl[1][q] + sl[2][q] + sl[3][q];
    float inv = 1.f / l;   // diagonal always allowed -> l > 0
    float4 ov;
    ov.x = u[0].sO[hd0][q]     + u[1].sO[hd0][q]     + u[2].sO[hd0][q]     + u[3].sO[hd0][q];
    ov.y = u[0].sO[hd0 + 1][q] + u[1].sO[hd0 + 1][q] + u[2].sO[hd0 + 1][q] + u[3].sO[hd0 + 1][q];
    ov.z = u[0].sO[hd0 + 2][q] + u[1].sO[hd0 + 2][q] + u[2].sO[hd0 + 2][q] + u[3].sO[hd0 + 2][q];
    ov.w = u[0].sO[hd0 + 3][q] + u[1].sO[hd0 + 3][q] + u[2].sO[hd0 + 3][q] + u[3].sO[hd0 + 3][q];
    uint2 ob;
    ob.x = pk_bf16(ov.x * inv, ov.y * inv);
    ob.y = pk_bf16(ov.z * inv, ov.w * inv);
    *(uint2*)(Om + (size_t)(q0 + q) * DMODEL + h * HDIM + hd0) = ob;
}

// ---------------------------------------------------------------------------
// Dispatch 3: post-attention chain per 16-row stripe, 512 threads/block.
// Stage A removed: Wo-GEMM A-operand read directly from bf16 Omb.
__global__ __launch_bounds__(512) void mega_kernel(
        const short* __restrict__ Omb,
        const float* __restrict__ X,
        const short* __restrict__ Wob, const short* __restrict__ W1b,
        const short* __restrict__ W2b,
        const float* __restrict__ bo,
        const float* __restrict__ g1, const float* __restrict__ be1,
        const float* __restrict__ b1, const float* __restrict__ b2,
        const float* __restrict__ g2, const float* __restrict__ be2,
        float* __restrict__ out) {
    __shared__ short sR[16 * SR_S];
    __shared__ float sH[16 * SH_S];
    __shared__ short sY[16 * SY_S];

    const int tid = threadIdx.x;
    const int wv = tid >> 6, lane = tid & 63;
    const int quad = lane >> 4, col = lane & 15;
    const int n0 = blockIdx.x * 16;
    const int rr_ = tid >> 5, c8 = (tid & 31) * 8;
    const int n_ln = n0 + rr_;
    f32x4 zero = {0.f, 0.f, 0.f, 0.f};

    // ---- Stage A2: h = O · Wo^T + bo (wave: 16 x 32; A from global) ----
    {
        const int o0 = wv * 32;
        f32x4 acc[2] = {zero, zero};
#pragma unroll
        for (int k0 = 0; k0 < DMODEL; k0 += 32) {
            s16x8 af = *(const s16x8*)(Omb + (size_t)(n0 + col) * DMODEL + k0 + quad * 8);
#pragma unroll
            for (int t = 0; t < 2; ++t) {
                s16x8 bf = *(const s16x8*)(Wob + (size_t)(o0 + t * 16 + col) * DMODEL + k0 + quad * 8);
                acc[t] = __builtin_amdgcn_mfma_f32_16x16x32_bf16(af, bf, acc[t], 0, 0, 0);
            }
        }
#pragma unroll
        for (int t = 0; t < 2; ++t) {
            int o = o0 + t * 16 + col;
            float bv = bo[o];
#pragma unroll
            for (int r = 0; r < 4; ++r)
                sH[(quad * 4 + r) * SH_S + o] = acc[t][r] + bv;
        }
    }
    __syncthreads();

    // ---- LN1: y1 = LN(x + h); 8 f32/thread in regs, bf16 -> sY ----
    float y1v[8];
    {
        const float* xp = X + (size_t)n_ln * DMODEL + c8;
        float v[8];
        float s = 0.f;
#pragma unroll
        for (int j = 0; j < 2; ++j) {
            float4 xv = ((const float4*)xp)[j];
            float4 hv = *(const float4*)&sH[rr_ * SH_S + c8 + j * 4];
            v[j * 4 + 0] = xv.x + hv.x; v[j * 4 + 1] = xv.y + hv.y;
            v[j * 4 + 2] = xv.z + hv.z; v[j * 4 + 3] = xv.w + hv.w;
            s += v[j * 4] + v[j * 4 + 1] + v[j * 4 + 2] + v[j * 4 + 3];
        }
#pragma unroll
        for (int m = 1; m < 32; m <<= 1) s += __shfl_xor(s, m, 64);
        float mean = s * (1.f / 256.f);
        float q = 0.f;
#pragma unroll
        for (int i = 0; i < 8; ++i) { v[i] -= mean; q += v[i] * v[i]; }
#pragma unroll
        for (int m = 1; m < 32; m <<= 1) q += __shfl_xor(q, m, 64);
        float rstd = rsqrtf(q * (1.f / 256.f) + 1e-5f);
        const float* gp = g1 + c8;
        const float* bp = be1 + c8;
        s16x8 w;
#pragma unroll
        for (int j = 0; j < 2; ++j) {
            float4 gv = ((const float4*)gp)[j];
            float4 bev = ((const float4*)bp)[j];
            float a0 = v[j * 4 + 0] * rstd * gv.x + bev.x;
            float a1 = v[j * 4 + 1] * rstd * gv.y + bev.y;
            float a2 = v[j * 4 + 2] * rstd * gv.z + bev.z;
            float a3 = v[j * 4 + 3] * rstd * gv.w + bev.w;
            y1v[j * 4 + 0] = a0; y1v[j * 4 + 1] = a1;
            y1v[j * 4 + 2] = a2; y1v[j * 4 + 3] = a3;
            *((unsigned*)&w + j * 2 + 0) = pk_bf16(a0, a1);
            *((unsigned*)&w + j * 2 + 1) = pk_bf16(a2, a3);
        }
        *(s16x8*)&sY[rr_ * SY_S + c8] = w;
    }
    __syncthreads();

    // ---- Stage B: relu(y1 · W1^T + b1) -> sR (wave: 16 x 64) ----
    {
        const int o0 = wv * 64;
        f32x4 acc[4] = {zero, zero, zero, zero};
#pragma unroll
        for (int k0 = 0; k0 < DMODEL; k0 += 32) {
            s16x8 af = *(const s16x8*)&sY[col * SY_S + k0 + quad * 8];
#pragma unroll
            for (int t = 0; t < 4; ++t) {
                s16x8 bf = *(const s16x8*)(W1b + (size_t)(o0 + t * 16 + col) * DMODEL + k0 + quad * 8);
                acc[t] = __builtin_amdgcn_mfma_f32_16x16x32_bf16(af, bf, acc[t], 0, 0, 0);
            }
        }
#pragma unroll
        for (int t = 0; t < 4; ++t) {
            int o = o0 + t * 16 + col;
            float bv = b1[o];
#pragma unroll
            for (int r = 0; r < 4; ++r)
                sR[(quad * 4 + r) * SR_S + o] = bf16r(fmaxf(acc[t][r] + bv, 0.f));
        }
    }
    __syncthreads();

    // ---- Stage C: t2 = r · W2^T + b2 (wave: 16 x 32, K=512) -> sH ----
    {
        const int o0 = wv * 32;
        f32x4 acc[2] = {zero, zero};
#pragma unroll
        for (int k0 = 0; k0 < 512; k0 += 32) {
            s16x8 af = *(const s16x8*)&sR[col * SR_S + k0 + quad * 8];
#pragma unroll
            for (int t = 0; t < 2; ++t) {
                s16x8 bf = *(const s16x8*)(W2b + (size_t)(o0 + t * 16 + col) * 512 + k0 + quad * 8);
                acc[t] = __builtin_amdgcn_mfma_f32_16x16x32_bf16(af, bf, acc[t], 0, 0, 0);
            }
        }
#pragma unroll
        for (int t = 0; t < 2; ++t) {
            int o = o0 + t * 16 + col;
            float bv = b2[o];
#pragma unroll
            for (int r = 0; r < 4; ++r)
                sH[(quad * 4 + r) * SH_S + o] = acc[t][r] + bv;
        }
    }
    __syncthreads();

    // ---- LN2: out = LN(y1 + t2) ----
    {
        float v[8];
        float s = 0.f;
#pragma unroll
        for (int j = 0; j < 2; ++j) {
            float4 hv = *(const float4*)&sH[rr_ * SH_S + c8 + j * 4];
            v[j * 4 + 0] = y1v[j * 4 + 0] + hv.x; v[j * 4 + 1] = y1v[j * 4 + 1] + hv.y;
            v[j * 4 + 2] = y1v[j * 4 + 2] + hv.z; v[j * 4 + 3] = y1v[j * 4 + 3] + hv.w;
            s += v[j * 4] + v[j * 4 + 1] + v[j * 4 + 2] + v[j * 4 + 3];
        }
#pragma unroll
        for (int m = 1; m < 32; m <<= 1) s += __shfl_xor(s, m, 64);
        float mean = s * (1.f / 256.f);
        float q = 0.f;
#pragma unroll
        for (int i = 0; i < 8; ++i) { v[i] -= mean; q += v[i] * v[i]; }
#pragma unroll
        for (int m = 1; m < 32; m <<= 1) q += __shfl_xor(q, m, 64);
        float rstd = rsqrtf(q * (1.f / 256.f) + 1e-5f);
        const float* gp = g2 + c8;
        const float* bp = be2 + c8;
        float* op = out + (size_t)n_ln * DMODEL + c8;
#pragma unroll
        for (int j = 0; j < 2; ++j) {
            float4 gv = ((const float4*)gp)[j];
            float4 bev = ((const float4*)bp)[j];
            float4 y;
            y.x = v[j * 4 + 0] * rstd * gv.x + bev.x;
            y.y = v[j * 4 + 1] * rstd * gv.y + bev.y;
            y.z = v[j * 4 + 2] * rstd * gv.z + bev.z;
            y.w = v[j * 4 + 3] * rstd * gv.w + bev.w;
            ((float4*)op)[j] = y;
        }
    }
}

// ---------------------------------------------------------------------------
extern "C" void kernel_launch(void* const* d_in, const int* in_sizes, int n_in,
                              void* d_out, int out_size, void* d_ws, size_t ws_size,
                              hipStream_t stream) {
    const float* x   = (const float*)d_in[0];
    const int*   adj = (const int*)d_in[1];
    const float* Wq  = (const float*)d_in[2];
    const float* Wk  = (const float*)d_in[3];
    const float* Wv  = (const float*)d_in[4];
    const float* bq  = (const float*)d_in[5];
    const float* bk  = (const float*)d_in[6];
    const float* bv  = (const float*)d_in[7];
    const float* Wo  = (const float*)d_in[8];
    const float* bo  = (const float*)d_in[9];
    const float* g1  = (const float*)d_in[10];
    const float* be1 = (const float*)d_in[11];
    const float* W1  = (const float*)d_in[12];
    const float* b1  = (const float*)d_in[13];
    const float* W2  = (const float*)d_in[14];
    const float* b2  = (const float*)d_in[15];
    const float* g2  = (const float*)d_in[16];
    const float* be2 = (const float*)d_in[17];
    float* out = (float*)d_out;

    char* p = (char*)d_ws;
    unsigned* mask = (unsigned*)p; p += (size_t)NROWS * 128 * 4;   //  2 MB
    short* Wb   = (short*)p;       p += (size_t)327680 * 2;        // .64 MB
    short* Qb   = (short*)p;       p += (size_t)NM * 2;            //  2 MB
    short* Kb   = (short*)p;       p += (size_t)NM * 2;            //  2 MB
    short* Vswz = (short*)p;       p += (size_t)NM * 2;            //  2 MB
    short* Omb  = (short*)p;       p += (size_t)NM * 2;            //  2 MB

    qkvprep_kernel<<<dim3(2976), dim3(256), 0, stream>>>(
        x, Wq, Wk, Wv, bq, bk, bv, adj, mask, Wo, W1, W2, Wb, Qb, Kb, Vswz);
    attn_kernel<<<dim3(1024), dim3(256), 0, stream>>>(Qb, Kb, Vswz, mask, Omb);
    mega_kernel<<<dim3(256), dim3(512), 0, stream>>>(
        Omb, x, Wb, Wb + 65536, Wb + 196608,
        bo, g1, be1, b1, b2, g2, be2, out);
}